// Round 10
// baseline (1292.363 us; speedup 1.0000x reference)
//
#include <hip/hip_runtime.h>
#include <math.h>

// SchNet forward, MI355X. Round 21 = r19 base + async global_load_lds B
// staging (dbuf).
// r20 evidence: TN=128 regressed (53.3->60.3us): FETCH unchanged at 18.2MB
// (A re-reads were already L2/L3-absorbed -> wide tile saved no HBM) and
// occupancy fell 40->21% (24KB LDS + 800-block tail). Tile geometry is
// exhausted; 64x64/1600 blocks is load-balance-optimal. REVERTED to r19.
// r19 counters: VALUBusy 52% top pipe, MfmaUtil 17%, conflicts 0. Per chunk
// each thread spends 2 B-loads->VGPR + 2 B ds_writes = pure copy overhead.
// Change: B staging via __builtin_amdgcn_global_load_lds width=16 (B is
// pre-tiled identity lane-linear = exactly the wave-uniform-base + lane*16
// pattern the instruction requires). No VGPR round trip, no ds_write insts.
// B double-buffered: issue chunk i+1 right after barrier1 so latency
// overlaps the MFMA region (drained at barrier2). A path (swizzled LDS,
// v_perm unpack, single-buffered) byte-identical to r19. LDS 24KB,
// lb(256,6) -> 6 blocks/CU. Numerics bit-identical.
// Stack: segment pool, batched tab GEMMs, packed bf16 hi/lo residual,
// 64x64 tiles, HP=608, XCD swizzle, CSR gather, pre-tiled fragment-major
// B weights, swizzled-A LDS, filter-table + lerp, split-K pool matmul
// (absmax 2.4e-4 vs 1.44e-3 budget).

#define N_ATOMS 10000
#define E_EDGES 64000
#define B_MOLS  128
#define H_DIM   600
#define HP      608            // padded leading dim (608*4B = 38 sectors)
#define G_DIM   50
#define L_LAYERS 6
#define M_TAB   1024
#define DMAX    8.67f
#define LOG2C   0.69314718056f

#define TM 64
#define TN 64
#define TK 32

// B tile geometry: 64 cols x 32 k, fragment-major, hi plane then lo plane
#define BTILE 4096     // shorts per tile (2 planes x 2048)
#define NTILES_H 10    // col tiles for Nc=600
#define KT_BIG 19      // k tiles for K=608
#define KT_W1  2       // k tiles for K=64
#define BSTRIDE_BIG (NTILES_H * KT_BIG * BTILE)   // 778,240 shorts / layer
#define BSTRIDE_W1  (NTILES_H * KT_W1  * BTILE)   // 81,920 shorts / layer

typedef __attribute__((ext_vector_type(8))) short bf16x8;
typedef __attribute__((ext_vector_type(4))) float f32x4;

__device__ __forceinline__ float sspf(float x) {
    return fmaxf(x, 0.0f) + log1pf(expf(-fabsf(x))) - LOG2C;
}
__device__ __forceinline__ short f2bf(float x) {
    unsigned u = __float_as_uint(x);
    unsigned r = (u + 0x7FFF + ((u >> 16) & 1)) >> 16;   // RNE
    return (short)r;
}
__device__ __forceinline__ float bf2f(short h) {
    return __uint_as_float(((unsigned)(unsigned short)h) << 16);
}
__device__ __forceinline__ int packsplit(float x) {
    short hi = f2bf(x);
    short lo = f2bf(x - bf2f(hi));
    return ((int)hi << 16) | ((int)lo & 0xffff);
}
__device__ __forceinline__ float unpackf(int p) {
    float fh = __uint_as_float((unsigned)p & 0xffff0000u);
    float fl = __uint_as_float(((unsigned)p) << 16);
    return fh + fl;
}

// async global->LDS, 16B per lane; lds base must be wave-uniform
// (HW computes dest = base + lane*16). Guide §5 / m97 pattern.
__device__ __forceinline__ void gload16(const short* g, short* l)
{
    __builtin_amdgcn_global_load_lds(
        (const __attribute__((address_space(1))) void*)g,
        (__attribute__((address_space(3))) void*)l, 16, 0, 0);
}

// 8 packed ints -> hi-plane int4 + lo-plane int4 via v_perm_b32
// (verified bit-exact on HW in r14/r15)
__device__ __forceinline__ void unpack_perm(const int4& p0, const int4& p1,
                                            int4& hi, int4& lo)
{
    hi.x = (int)__builtin_amdgcn_perm((unsigned)p0.y, (unsigned)p0.x, 0x07060302u);
    hi.y = (int)__builtin_amdgcn_perm((unsigned)p0.w, (unsigned)p0.z, 0x07060302u);
    hi.z = (int)__builtin_amdgcn_perm((unsigned)p1.y, (unsigned)p1.x, 0x07060302u);
    hi.w = (int)__builtin_amdgcn_perm((unsigned)p1.w, (unsigned)p1.z, 0x07060302u);
    lo.x = (int)__builtin_amdgcn_perm((unsigned)p0.y, (unsigned)p0.x, 0x05040100u);
    lo.y = (int)__builtin_amdgcn_perm((unsigned)p0.w, (unsigned)p0.z, 0x05040100u);
    lo.z = (int)__builtin_amdgcn_perm((unsigned)p1.y, (unsigned)p1.x, 0x05040100u);
    lo.w = (int)__builtin_amdgcn_perm((unsigned)p1.w, (unsigned)p1.z, 0x05040100u);
}

// ---------------------------------------------------------------- MFMA GEMM
// outP = packsplit(op(A @ B + bias [+ unpack(outP)])). A: packed int [Ma][lda]
// (zero-padded cols). Bt: fragment-major tiles [nt][kt][hi2048|lo2048],
// zero-padded cols/k. K % 32 == 0. Output ld = HP, pad cols 0. 1D grid,
// XCD swizzle. A staged via swizzled layout s(row,kq)=row*4+((kq+(row>>1))&3)
// (conflict-free both sides, r19-proven). B staged via global_load_lds
// width=16 into a double buffer (identity lane-linear: lane l of wave w ->
// byte w*1024 + l*16, matching the pre-tiled global layout). Issue of
// chunk i+1 sits after barrier1 so its latency overlaps the MFMA region.
// A rows clamped; OOB masked by epilogue.
template<bool BIAS, bool ACT, bool ACCUM>
__global__ __launch_bounds__(256, 6)
void gemm_mfma(const int* __restrict__ A, int lda,
               const short* __restrict__ Bt,
               const float* __restrict__ bias,
               int* __restrict__ outP,
               int Ma, int K, int Nc)
{
    const int NT = (Nc + TN - 1) / TN;
    const int f = blockIdx.x;
    const int xcd = f & 7, s = f >> 3;
    const int n0 = (s % NT) * TN;
    const int m0 = (xcd + 8 * (s / NT)) * TM;
    if (m0 >= Ma) return;
    const int KT = (K + 31) >> 5;

    __shared__ __align__(16) short As[2][2048];
    __shared__ __align__(16) short Bs[2][4096];   // [buf][hi2048|lo2048]

    const int tid = threadIdx.x;
    const int lane = tid & 63, wid = tid >> 6;
    const int wm = (wid >> 1) * 32, wn = (wid & 1) * 32;
    const int l15 = lane & 15, quad = lane >> 4;
    const int srow = tid >> 2;          // 0..63 (coalesced global map)
    const int skk  = (tid & 3) << 3;    // 0,8,16,24
    // swizzled A write index: s = srow*4 + ((kq + (srow>>1)) & 3), shorts = s*8
    const int awidx = srow * 32 + ((((tid & 3) + (tid >> 3)) & 3) << 3);
    // swizzled A read offset (per-lane, rg-invariant)
    const int aoff  = l15 * 32 + (((quad + (l15 >> 1)) & 3) << 3);
    const int wb = wid * 512;           // wave-uniform LDS base (shorts)

    const int gm = min(m0 + srow, Ma - 1);
    const int*   aPtr = A + (size_t)gm * lda + skk;
    const short* bPtr = Bt + ((size_t)(n0 >> 6) * KT) * BTILE + tid * 8;

    f32x4 acc[2][2];
    #pragma unroll
    for (int i = 0; i < 2; ++i)
        #pragma unroll
        for (int j = 0; j < 2; ++j)
            acc[i][j] = (f32x4){0.f, 0.f, 0.f, 0.f};

    int4 ra0, ra1;

    // prefetch chunk 0: B via async gload_lds, A into regs
    gload16(bPtr,        &Bs[0][wb]);
    gload16(bPtr + 2048, &Bs[0][2048 + wb]);
    ra0 = *(const int4*)aPtr; ra1 = *(const int4*)(aPtr + 4);
    aPtr += TK; bPtr += BTILE;

    int cur = 0;
    for (int k0 = 0; k0 < K; k0 += TK) {
        {
            int4 hi, lo;
            unpack_perm(ra0, ra1, hi, lo);
            *(int4*)&As[0][awidx] = hi;
            *(int4*)&As[1][awidx] = lo;
        }
        if (k0 + TK < K) {
            ra0 = *(const int4*)aPtr; ra1 = *(const int4*)(aPtr + 4);
            aPtr += TK;
        }
        __syncthreads();    // B_i gload_lds drained; A writes visible

        if (k0 + TK < K) {  // issue B_{i+1}; latency overlaps MFMA below
            gload16(bPtr,        &Bs[cur ^ 1][wb]);
            gload16(bPtr + 2048, &Bs[cur ^ 1][2048 + wb]);
            bPtr += BTILE;
        }

        bf16x8 a_h[2], a_l[2], b_h[2], b_l[2];
        #pragma unroll
        for (int mi = 0; mi < 2; ++mi) {
            int ridx = ((wm >> 4) + mi) * 512 + aoff;
            a_h[mi] = *(const bf16x8*)&As[0][ridx];
            a_l[mi] = *(const bf16x8*)&As[1][ridx];
        }
        #pragma unroll
        for (int ni = 0; ni < 2; ++ni) {
            int ridx = ((wn >> 4) + ni) * 512 + lane * 8;
            b_h[ni] = *(const bf16x8*)&Bs[cur][ridx];
            b_l[ni] = *(const bf16x8*)&Bs[cur][2048 + ridx];
        }

        #pragma unroll
        for (int mi = 0; mi < 2; ++mi)
            #pragma unroll
            for (int ni = 0; ni < 2; ++ni) {
                acc[mi][ni] = __builtin_amdgcn_mfma_f32_16x16x32_bf16(
                    a_h[mi], b_h[ni], acc[mi][ni], 0, 0, 0);
                acc[mi][ni] = __builtin_amdgcn_mfma_f32_16x16x32_bf16(
                    a_h[mi], b_l[ni], acc[mi][ni], 0, 0, 0);
                acc[mi][ni] = __builtin_amdgcn_mfma_f32_16x16x32_bf16(
                    a_l[mi], b_h[ni], acc[mi][ni], 0, 0, 0);
            }
        __syncthreads();    // protects As overwrite; drains B_{i+1}
        cur ^= 1;
    }

    #pragma unroll
    for (int mi = 0; mi < 2; ++mi) {
        #pragma unroll
        for (int r = 0; r < 4; ++r) {
            int row = m0 + wm + mi * 16 + quad * 4 + r;
            if (row >= Ma) continue;
            #pragma unroll
            for (int ni = 0; ni < 2; ++ni) {
                int col = n0 + wn + ni * 16 + l15;
                if (col >= HP) continue;
                size_t idx = (size_t)row * HP + col;
                float v = 0.0f;
                if (col < Nc) {
                    v = acc[mi][ni][r];
                    if constexpr (BIAS) v += bias[col];
                    if constexpr (ACT)  v = sspf(v);
                    if constexpr (ACCUM) v += unpackf(outP[idx]);
                }
                outP[idx] = packsplit(v);
            }
        }
    }
}

// Batched slab GEMM over all L layers stacked in M (1024 rows per layer).
// SHAREDA: A rows are (m % 1024). Same swizzled-A + async-B scheme.
template<bool SHAREDA, bool ACT>
__global__ __launch_bounds__(256, 6)
void gemm_tab(const int* __restrict__ A, int lda,
              const short* __restrict__ BtBase, size_t bstride,
              const float* __restrict__ biasBase,
              int* __restrict__ outP,
              int Ma, int K, int Nc)
{
    const int NT = (Nc + TN - 1) / TN;
    const int f = blockIdx.x;
    const int xcd = f & 7, s = f >> 3;
    const int n0 = (s % NT) * TN;
    const int m0 = (xcd + 8 * (s / NT)) * TM;
    if (m0 >= Ma) return;
    const int KT = (K + 31) >> 5;

    const int layer = m0 >> 10;                       // 1024 rows per layer
    const int arow0 = SHAREDA ? (m0 & 1023) : m0;
    const short* __restrict__ Bt = BtBase + (size_t)layer * bstride;
    const float* __restrict__ bias = biasBase + (size_t)layer * H_DIM;

    __shared__ __align__(16) short As[2][2048];
    __shared__ __align__(16) short Bs[2][4096];

    const int tid = threadIdx.x;
    const int lane = tid & 63, wid = tid >> 6;
    const int wm = (wid >> 1) * 32, wn = (wid & 1) * 32;
    const int l15 = lane & 15, quad = lane >> 4;
    const int srow = tid >> 2;
    const int skk  = (tid & 3) << 3;
    const int awidx = srow * 32 + ((((tid & 3) + (tid >> 3)) & 3) << 3);
    const int aoff  = l15 * 32 + (((quad + (l15 >> 1)) & 3) << 3);
    const int wb = wid * 512;

    const int*   aPtr = A + (size_t)(arow0 + srow) * lda + skk;
    const short* bPtr = Bt + ((size_t)(n0 >> 6) * KT) * BTILE + tid * 8;

    f32x4 acc[2][2];
    #pragma unroll
    for (int i = 0; i < 2; ++i)
        #pragma unroll
        for (int j = 0; j < 2; ++j)
            acc[i][j] = (f32x4){0.f, 0.f, 0.f, 0.f};

    int4 ra0, ra1;

    gload16(bPtr,        &Bs[0][wb]);
    gload16(bPtr + 2048, &Bs[0][2048 + wb]);
    ra0 = *(const int4*)aPtr; ra1 = *(const int4*)(aPtr + 4);
    aPtr += TK; bPtr += BTILE;

    int cur = 0;
    for (int k0 = 0; k0 < K; k0 += TK) {
        {
            int4 hi, lo;
            unpack_perm(ra0, ra1, hi, lo);
            *(int4*)&As[0][awidx] = hi;
            *(int4*)&As[1][awidx] = lo;
        }
        if (k0 + TK < K) {
            ra0 = *(const int4*)aPtr; ra1 = *(const int4*)(aPtr + 4);
            aPtr += TK;
        }
        __syncthreads();

        if (k0 + TK < K) {
            gload16(bPtr,        &Bs[cur ^ 1][wb]);
            gload16(bPtr + 2048, &Bs[cur ^ 1][2048 + wb]);
            bPtr += BTILE;
        }

        bf16x8 a_h[2], a_l[2], b_h[2], b_l[2];
        #pragma unroll
        for (int mi = 0; mi < 2; ++mi) {
            int ridx = ((wm >> 4) + mi) * 512 + aoff;
            a_h[mi] = *(const bf16x8*)&As[0][ridx];
            a_l[mi] = *(const bf16x8*)&As[1][ridx];
        }
        #pragma unroll
        for (int ni = 0; ni < 2; ++ni) {
            int ridx = ((wn >> 4) + ni) * 512 + lane * 8;
            b_h[ni] = *(const bf16x8*)&Bs[cur][ridx];
            b_l[ni] = *(const bf16x8*)&Bs[cur][2048 + ridx];
        }
        #pragma unroll
        for (int mi = 0; mi < 2; ++mi)
            #pragma unroll
            for (int ni = 0; ni < 2; ++ni) {
                acc[mi][ni] = __builtin_amdgcn_mfma_f32_16x16x32_bf16(
                    a_h[mi], b_h[ni], acc[mi][ni], 0, 0, 0);
                acc[mi][ni] = __builtin_amdgcn_mfma_f32_16x16x32_bf16(
                    a_h[mi], b_l[ni], acc[mi][ni], 0, 0, 0);
                acc[mi][ni] = __builtin_amdgcn_mfma_f32_16x16x32_bf16(
                    a_l[mi], b_h[ni], acc[mi][ni], 0, 0, 0);
            }
        __syncthreads();
        cur ^= 1;
    }

    #pragma unroll
    for (int mi = 0; mi < 2; ++mi) {
        #pragma unroll
        for (int r = 0; r < 4; ++r) {
            int row = m0 + wm + mi * 16 + quad * 4 + r;
            if (row >= Ma) continue;
            #pragma unroll
            for (int ni = 0; ni < 2; ++ni) {
                int col = n0 + wn + ni * 16 + l15;
                if (col >= HP) continue;
                float v = 0.0f;
                if (col < Nc) {
                    v = acc[mi][ni][r] + bias[col];
                    if constexpr (ACT) v = sspf(v);
                }
                outP[(size_t)row * HP + col] = packsplit(v);
            }
        }
    }
}

static inline dim3 mfma_grid(int Ma, int Nc) {
    int MB = (Ma + TM - 1) / TM;
    int NT = (Nc + TN - 1) / TN;
    int Ys = ((MB + 7) / 8) * 8;
    return dim3(Ys * NT);
}

// ------------------------------------------------- final pool matmul (tiny)
// pooled[128][600] @ pool_w[600][600] + b. 4-way K-split per column + LDS
// reduce: 1280 blocks (5/CU), serial chain 150 deep instead of 600.
__global__ __launch_bounds__(256)
void pool_mm2_k(const float* __restrict__ A, const float* __restrict__ W,
                const float* __restrict__ bias, float* __restrict__ out)
{
    __shared__ float arow[H_DIM];
    __shared__ float red[4][64];
    const int b = blockIdx.y;
    const int ct = blockIdx.x;             // 10 tiles of 64 cols
    const int t = threadIdx.x;
    const int ci = t & 63, kq = t >> 6;    // wave-uniform K quarter
    for (int k = t; k < H_DIM; k += 256)
        arow[k] = A[(size_t)b * H_DIM + k];
    __syncthreads();
    const int col = min(ct * 64 + ci, H_DIM - 1);   // clamp; store guarded
    const float* wp = W + (size_t)(kq * 150) * H_DIM + col;
    float s = 0.f;
    #pragma unroll 6
    for (int k = 0; k < 150; ++k)
        s = fmaf(arow[kq * 150 + k], wp[(size_t)k * H_DIM], s);
    red[kq][ci] = s;
    __syncthreads();
    if (kq == 0) {
        int c = ct * 64 + ci;
        if (c < H_DIM)
            out[(size_t)b * H_DIM + c] =
                red[0][ci] + red[1][ci] + red[2][ci] + red[3][ci] + bias[c];
    }
}

// ---------------------------------------------------------------- weight prep
// w1 -> fragment-major tiles: per layer [nt(10)][kt(2)][hi2048|lo2048]
__global__ __launch_bounds__(256)
void wts_w1_k(const float* __restrict__ w_all, short* __restrict__ w1t)
{
    __shared__ short th[64][65], tl[64][65];
    const int layer = blockIdx.z;
    const int nt = blockIdx.y;
    const float* w = w_all + (size_t)layer * G_DIM * H_DIM;
    short* outb = w1t + (size_t)layer * BSTRIDE_W1 + (size_t)nt * KT_W1 * BTILE;
    const int n0 = nt * 64;
    const int tid = threadIdx.x;
    #pragma unroll
    for (int p = 0; p < 4; ++p) {
        int k = p * 16 + (tid >> 4);
        int n4 = (tid & 15) << 2;
        float4 v = make_float4(0.f, 0.f, 0.f, 0.f);
        if (k < G_DIM && n0 + n4 + 3 < H_DIM)
            v = *(const float4*)(w + (size_t)k * H_DIM + n0 + n4);
        int px = packsplit(v.x), py = packsplit(v.y);
        int pz = packsplit(v.z), pw = packsplit(v.w);
        th[n4 + 0][k] = (short)(px >> 16); tl[n4 + 0][k] = (short)px;
        th[n4 + 1][k] = (short)(py >> 16); tl[n4 + 1][k] = (short)py;
        th[n4 + 2][k] = (short)(pz >> 16); tl[n4 + 2][k] = (short)pz;
        th[n4 + 3][k] = (short)(pw >> 16); tl[n4 + 3][k] = (short)pw;
    }
    __syncthreads();
    #pragma unroll
    for (int p = 0; p < 4; ++p) {
        int n = p * 16 + (tid >> 4);
        int k4 = (tid & 15) << 2;           // 0..60
        int kt = k4 >> 5, kk = k4 & 31;
        int idx = (n >> 4) * 512 + (kk >> 3) * 128 + (n & 15) * 8 + (kk & 7);
        short* tb = outb + (size_t)kt * BTILE;
        short4 sh = { th[n][k4], th[n][k4 + 1], th[n][k4 + 2], th[n][k4 + 3] };
        short4 sl = { tl[n][k4], tl[n][k4 + 1], tl[n][k4 + 2], tl[n][k4 + 3] };
        *(short4*)(tb + idx)        = sh;
        *(short4*)(tb + 2048 + idx) = sl;
    }
}

// big weights -> fragment-major tiles: per layer [nt(10)][kt(19)][hi|lo]
__global__ __launch_bounds__(256)
void wts_big_k(const float* __restrict__ w2, const float* __restrict__ l1,
               const float* __restrict__ l2, const float* __restrict__ iw,
               short* __restrict__ o2, short* __restrict__ o1,
               short* __restrict__ ol2, short* __restrict__ oi)
{
    __shared__ short th[64][65], tl[64][65];
    const int z = blockIdx.z, type = z / L_LAYERS, layer = z % L_LAYERS;
    const float* w; short* ob;
    if (type == 0)      { w = w2; ob = o2; }
    else if (type == 1) { w = l1; ob = o1; }
    else if (type == 2) { w = l2; ob = ol2; }
    else                { w = iw; ob = oi; }
    w  += (size_t)layer * H_DIM * H_DIM;
    ob += (size_t)layer * BSTRIDE_BIG;
    const int k0 = blockIdx.x * 64, nt = blockIdx.y, n0 = nt * 64;
    const int tid = threadIdx.x;
    #pragma unroll
    for (int p = 0; p < 4; ++p) {
        int k = p * 16 + (tid >> 4);
        int n4 = (tid & 15) << 2;
        float4 v = make_float4(0.f, 0.f, 0.f, 0.f);
        if (k0 + k < H_DIM && n0 + n4 + 3 < H_DIM)
            v = *(const float4*)(w + (size_t)(k0 + k) * H_DIM + n0 + n4);
        int px = packsplit(v.x), py = packsplit(v.y);
        int pz = packsplit(v.z), pw = packsplit(v.w);
        th[n4 + 0][k] = (short)(px >> 16); tl[n4 + 0][k] = (short)px;
        th[n4 + 1][k] = (short)(py >> 16); tl[n4 + 1][k] = (short)py;
        th[n4 + 2][k] = (short)(pz >> 16); tl[n4 + 2][k] = (short)pz;
        th[n4 + 3][k] = (short)(pw >> 16); tl[n4 + 3][k] = (short)pw;
    }
    __syncthreads();
    #pragma unroll
    for (int p = 0; p < 4; ++p) {
        int n = p * 16 + (tid >> 4);
        int k4 = (tid & 15) << 2;
        int kg = k0 + k4;
        if (kg >= KT_BIG * 32) continue;            // k0=576 block: k4<32 only
        int kt = kg >> 5, kk = kg & 31;
        int idx = (n >> 4) * 512 + (kk >> 3) * 128 + (n & 15) * 8 + (kk & 7);
        short* tb = ob + ((size_t)nt * KT_BIG + kt) * BTILE;
        short4 sh = { th[n][k4], th[n][k4 + 1], th[n][k4 + 2], th[n][k4 + 3] };
        short4 sl = { tl[n][k4], tl[n][k4 + 1], tl[n][k4 + 2], tl[n][k4 + 3] };
        *(short4*)(tb + idx)        = sh;
        *(short4*)(tb + 2048 + idx) = sl;
    }
}

// ---------------------------------------------------------------- helpers
__global__ __launch_bounds__(256)
void init_h_k(const int* __restrict__ z, const float* __restrict__ emb,
              int* __restrict__ hP)
{
    int t = blockIdx.x * 256 + threadIdx.x;
    const int QC = HP / 4;   // 152
    if (t >= N_ATOMS * QC) return;
    int i = t / QC;
    int q = (t - i * QC) << 2;
    size_t idx = (size_t)i * HP + q;
    if (q < H_DIM) {
        float4 v = *(const float4*)(emb + (size_t)z[i] * H_DIM + q);
        *(int4*)(hP + idx) = make_int4(packsplit(v.x), packsplit(v.y),
                                       packsplit(v.z), packsplit(v.w));
    } else {
        *(int4*)(hP + idx) = make_int4(0, 0, 0, 0);
    }
}

// per-edge record: {src*HP, i0*HP, a = C - f*C, b = f*C}
__global__ __launch_bounds__(256)
void edge_geom_k(const float* __restrict__ pos, const int* __restrict__ src,
                 const int* __restrict__ dst, float4* __restrict__ einfo)
{
    int e = blockIdx.x * 256 + threadIdx.x;
    if (e >= E_EDGES) return;
    int s = src[e], d0 = dst[e];
    float dx = pos[s * 3 + 0] - pos[d0 * 3 + 0];
    float dy = pos[s * 3 + 1] - pos[d0 * 3 + 1];
    float dz = pos[s * 3 + 2] - pos[d0 * 3 + 2];
    float dist = sqrtf(dx * dx + dy * dy + dz * dz + 1e-12f);
    float cc = 0.5f * (cosf(dist * 0.31415926535f) + 1.0f);
    float u = dist * ((float)(M_TAB - 1) / DMAX);
    u = fminf(fmaxf(u, 0.0f), (float)(M_TAB - 1) - 0.001f);
    int i0 = (int)u;
    float fc = (u - (float)i0) * cc;
    einfo[e] = make_float4(__int_as_float(s * HP),
                           __int_as_float(i0 * HP),
                           cc - fc, fc);
}

__global__ __launch_bounds__(256)
void rbf_tab_k(int* __restrict__ rtabP)
{
    int t = blockIdx.x * 256 + threadIdx.x;
    if (t >= M_TAB * 64) return;
    int i = t >> 6, g = t & 63;
    float v = 0.0f;
    if (g < G_DIM) {
        float dg  = (float)i * (DMAX / (float)(M_TAB - 1));
        float off = (float)g * (10.0f / 49.0f);
        float x = dg - off;
        const float coeff = -0.5f * (49.0f / 10.0f) * (49.0f / 10.0f);
        v = expf(coeff * x * x);
    }
    rtabP[t] = packsplit(v);
}

// ---------------------------------------------------------------- CSR build
__global__ __launch_bounds__(256)
void hist_k(const int* __restrict__ dst, int* __restrict__ deg)
{
    int e = blockIdx.x * 256 + threadIdx.x;
    if (e >= E_EDGES) return;
    atomicAdd(&deg[dst[e]], 1);
}

__global__ __launch_bounds__(1024)
void scan_k(const int* __restrict__ deg, int* __restrict__ rowptr)
{
    __shared__ int sums[1024];
    int tid = threadIdx.x;
    const int CHUNK = (N_ATOMS + 1023) / 1024;
    int base = tid * CHUNK;
    int local[16];
    int s = 0;
    #pragma unroll
    for (int c = 0; c < 16; ++c) {
        if (c >= CHUNK) break;
        int idx = base + c;
        local[c] = s;
        s += (idx < N_ATOMS) ? deg[idx] : 0;
    }
    sums[tid] = s;
    __syncthreads();
    for (int off = 1; off < 1024; off <<= 1) {
        int v = (tid >= off) ? sums[tid - off] : 0;
        __syncthreads();
        sums[tid] += v;
        __syncthreads();
    }
    int prefix = (tid > 0) ? sums[tid - 1] : 0;
    #pragma unroll
    for (int c = 0; c < 16; ++c) {
        if (c >= CHUNK) break;
        int idx = base + c;
        if (idx <= N_ATOMS) rowptr[idx] = prefix + local[c];
    }
    if (tid == 1023) rowptr[N_ATOMS] = sums[1023];
}

__global__ __launch_bounds__(256)
void fill_k(const int* __restrict__ dst, const float4* __restrict__ einfo,
            const int* __restrict__ rowptr, int* __restrict__ cursor,
            float4* __restrict__ esorted)
{
    int e = blockIdx.x * 256 + threadIdx.x;
    if (e >= E_EDGES) return;
    int d0 = dst[e];
    int pos = rowptr[d0] + atomicAdd(&cursor[d0], 1);
    esorted[pos] = einfo[e];
}

// molecule boundaries via binary search over the SORTED batch array
__global__ __launch_bounds__(256)
void bounds_k(const int* __restrict__ batch, int* __restrict__ mrow)
{
    int b = threadIdx.x;
    if (b > B_MOLS) return;
    int lo = 0, hi = N_ATOMS;
    while (lo < hi) {
        int mid = (lo + hi) >> 1;
        if (batch[mid] < b) lo = mid + 1; else hi = mid;
    }
    mrow[b] = lo;
}

// ---------------------------------------------------------------- gather
__device__ __forceinline__ void gacc(float4& acc, const int* yP, const int* wtP,
                                     const float4& ei, int q)
{
    int srow = __float_as_int(ei.x);
    int wrow = __float_as_int(ei.y);
    float a = ei.z, b = ei.w;
    int4 yv = *(const int4*)(yP + srow + q);
    int4 w0 = *(const int4*)(wtP + wrow + q);
    int4 w1 = *(const int4*)(wtP + wrow + HP + q);
    acc.x += unpackf(yv.x) * (a * unpackf(w0.x) + b * unpackf(w1.x));
    acc.y += unpackf(yv.y) * (a * unpackf(w0.y) + b * unpackf(w1.y));
    acc.z += unpackf(yv.z) * (a * unpackf(w0.z) + b * unpackf(w1.z));
    acc.w += unpackf(yv.w) * (a * unpackf(w0.w) + b * unpackf(w1.w));
}

__global__ __launch_bounds__(256)
void gather_k(const int* __restrict__ yP, const int* __restrict__ wtP,
              const int* __restrict__ rowptr, const float4* __restrict__ esorted,
              int* __restrict__ aggP)
{
    int t = blockIdx.x * 256 + threadIdx.x;
    const int QC = HP / 4;   // 152
    if (t >= N_ATOMS * QC) return;
    int i = t / QC;
    int q = (t - i * QC) << 2;
    size_t idx = (size_t)i * HP + q;
    if (q >= H_DIM) { *(int4*)(aggP + idx) = make_int4(0, 0, 0, 0); return; }
    int j0 = rowptr[i], j1 = rowptr[i + 1];
    float4 a0 = make_float4(0.f, 0.f, 0.f, 0.f);
    float4 a1 = make_float4(0.f, 0.f, 0.f, 0.f);
    int j = j0;
    for (; j + 2 <= j1; j += 2) {
        float4 e0 = esorted[j], e1 = esorted[j + 1];
        gacc(a0, yP, wtP, e0, q);
        gacc(a1, yP, wtP, e1, q);
    }
    if (j < j1) gacc(a0, yP, wtP, esorted[j], q);
    a0.x += a1.x; a0.y += a1.y; a0.z += a1.z; a0.w += a1.w;
    *(int4*)(aggP + idx) = make_int4(packsplit(a0.x), packsplit(a0.y),
                                     packsplit(a0.z), packsplit(a0.w));
}

// ---------------------------------------------------------------- pool (segment mean, no atomics)
__global__ __launch_bounds__(256)
void pool_seg_k(const int* __restrict__ hP, const int* __restrict__ mrow,
                float* __restrict__ pooled)
{
    int b = blockIdx.x;
    int t = threadIdx.x;
    if (t >= 150) return;               // cols 600..607 are pad
    int q = t << 2;
    int a = mrow[b], a1 = mrow[b + 1];
    float cnt = (float)(a1 - a);
    float4 s0 = make_float4(0.f, 0.f, 0.f, 0.f);
    float4 s1 = make_float4(0.f, 0.f, 0.f, 0.f);
    for (; a + 2 <= a1; a += 2) {
        int4 p0 = *(const int4*)(hP + (size_t)a * HP + q);
        int4 p1 = *(const int4*)(hP + (size_t)(a + 1) * HP + q);
        s0.x += unpackf(p0.x); s0.y += unpackf(p0.y);
        s0.z += unpackf(p0.z); s0.w += unpackf(p0.w);
        s1.x += unpackf(p1.x); s1.y += unpackf(p1.y);
        s1.z += unpackf(p1.z); s1.w += unpackf(p1.w);
    }
    if (a < a1) {
        int4 p0 = *(const int4*)(hP + (size_t)a * HP + q);
        s0.x += unpackf(p0.x); s0.y += unpackf(p0.y);
        s0.z += unpackf(p0.z); s0.w += unpackf(p0.w);
    }
    float inv = 1.0f / fmaxf(cnt, 1.0f);
    float4 o = make_float4((s0.x + s1.x) * inv, (s0.y + s1.y) * inv,
                           (s0.z + s1.z) * inv, (s0.w + s1.w) * inv);
    *(float4*)(pooled + (size_t)b * H_DIM + q) = o;
}

// ---------------------------------------------------------------- launch
extern "C" void kernel_launch(void* const* d_in, const int* in_sizes, int n_in,
                              void* d_out, int out_size, void* d_ws, size_t ws_size,
                              hipStream_t stream)
{
    const int*   z      = (const int*)  d_in[0];
    const float* pos    = (const float*)d_in[1];
    const int*   batch  = (const int*)  d_in[2];
    const int*   eidx   = (const int*)  d_in[3];
    const float* emb    = (const float*)d_in[4];
    const float* mlp_w1 = (const float*)d_in[5];
    const float* mlp_b1 = (const float*)d_in[6];
    const float* mlp_w2 = (const float*)d_in[7];
    const float* mlp_b2 = (const float*)d_in[8];
    const float* lin1_w = (const float*)d_in[9];
    const float* lin2_w = (const float*)d_in[10];
    const float* lin2_b = (const float*)d_in[11];
    const float* intw   = (const float*)d_in[12];
    const float* intb   = (const float*)d_in[13];
    const float* poolw  = (const float*)d_in[14];
    const float* poolb  = (const float*)d_in[15];

    float* ws = (float*)d_ws;
    const size_t NHP = (size_t)N_ATOMS * HP;       // 6,080,000
    const size_t TABALL = (size_t)L_LAYERS * M_TAB * HP;   // 3,735,552

    int*   hP    = (int*)ws;                       // NHP
    int*   y1P   = (int*)(ws + NHP);               // NHP; aliases tP, ttabA
    int*   tP    = y1P;
    int*   ttabA = y1P;                            // prep-time alias (3.7M <= NHP)
    int*   aggP  = (int*)(ws + 2 * NHP);           // NHP
    // aggP region aliases — ONLY prep-phase data dead before first gather:
    float4* einfo  = (float4*)aggP;                          // 256,000 f
    int*    deg    = (int*)((float*)aggP + 300000);          // 10,000
    int*    cursor = (int*)((float*)aggP + 310000);          // 10,000
    short*  w1t    = (short*)((float*)aggP + 400000);        // 491,520 shorts
    int*   wtabA = (int*)(ws + 3 * NHP);           // TABALL (persistent)
    int*   rtabP = (int*)(ws + 3 * NHP + TABALL);  // M_TAB*64 = 65,536
    // big weight tiles (4 types x 6 layers x 778,240 shorts)
    short* wtT   = (short*)(ws + 3 * NHP + TABALL + (size_t)M_TAB * 64);
    short* w2t = wtT;
    short* l1t = w2t + (size_t)L_LAYERS * BSTRIDE_BIG;
    short* l2t = l1t + (size_t)L_LAYERS * BSTRIDE_BIG;
    short* itt = l2t + (size_t)L_LAYERS * BSTRIDE_BIG;
    // persistent tail (NOT aliased): esorted, pooled, rowptr, mrow
    float*  tailF   = (float*)(itt + (size_t)L_LAYERS * BSTRIDE_BIG);
    float4* esorted = (float4*)tailF;                        // 256,000 f
    float*  pooled  = tailF + 256000;                        // 76,800 f
    int*    rowptr  = (int*)(tailF + 332800);                // 10,001
    int*    mrow    = rowptr + 10001;                        // 129

    const int* src = eidx;
    const int* dst = eidx + E_EDGES;

    const dim3 blk(256);
    const int QC = HP / 4;
    const dim3 gN   = mfma_grid(N_ATOMS, H_DIM);            // 1600
    const dim3 gTab = mfma_grid(L_LAYERS * M_TAB, H_DIM);   // 960

    // ---- one-time prep (einfo/deg/cursor/w1t alias aggP: dead before gather)
    edge_geom_k<<<(E_EDGES + 255) / 256, blk, 0, stream>>>(pos, src, dst, einfo);
    hipMemsetAsync(deg, 0, 2 * N_ATOMS * sizeof(int), stream);
    hist_k <<<(E_EDGES + 255) / 256, blk, 0, stream>>>(dst, deg);
    scan_k <<<1, 1024, 0, stream>>>(deg, rowptr);
    fill_k <<<(E_EDGES + 255) / 256, blk, 0, stream>>>(dst, einfo, rowptr, cursor, esorted);
    bounds_k <<<1, 256, 0, stream>>>(batch, mrow);
    init_h_k <<<(N_ATOMS * QC + 255) / 256, blk, 0, stream>>>(z, emb, hP);
    rbf_tab_k<<<(M_TAB * 64 + 255) / 256,   blk, 0, stream>>>(rtabP);
    wts_w1_k  <<<dim3(1, 10, 6),   blk, 0, stream>>>(mlp_w1, w1t);
    wts_big_k <<<dim3(10, 10, 24), blk, 0, stream>>>(
        mlp_w2, lin1_w, lin2_w, intw, w2t, l1t, l2t, itt);

    // ---- all 6 layers' filter tables in 2 batched slab GEMMs
    gemm_tab<true, true><<<gTab, blk, 0, stream>>>(
        rtabP, 64, w1t, (size_t)BSTRIDE_W1, mlp_b1,
        ttabA, L_LAYERS * M_TAB, 64, H_DIM);
    gemm_tab<false, false><<<gTab, blk, 0, stream>>>(
        ttabA, HP, w2t, (size_t)BSTRIDE_BIG, mlp_b2,
        wtabA, L_LAYERS * M_TAB, HP, H_DIM);

    for (int k = 0; k < L_LAYERS; ++k) {
        const float* l2b = lin2_b + (size_t)k * H_DIM;
        const float* ib  = intb   + (size_t)k * H_DIM;
        const short* l1 = l1t + (size_t)k * BSTRIDE_BIG;
        const short* l2 = l2t + (size_t)k * BSTRIDE_BIG;
        const short* it = itt + (size_t)k * BSTRIDE_BIG;
        const int*   wtP = wtabA + (size_t)k * M_TAB * HP;

        // y1P = packsplit(h @ lin1)
        gemm_mfma<false, false, false><<<gN, blk, 0, stream>>>(
            hP, HP, l1, nullptr, y1P, N_ATOMS, HP, H_DIM);
        // aggP = packsplit(CSR-gather(y1 * W(d) * C))
        gather_k<<<(N_ATOMS * QC + 255) / 256, blk, 0, stream>>>(
            y1P, wtP, rowptr, esorted, aggP);
        // tP = packsplit(ssp(agg @ lin2 + b))   (aliases y1P)
        gemm_mfma<true, true, false><<<gN, blk, 0, stream>>>(
            aggP, HP, l2, l2b, tP, N_ATOMS, HP, H_DIM);
        // hP = packsplit(unpack(hP) + t @ int_w + ib)
        gemm_mfma<true, false, true><<<gN, blk, 0, stream>>>(
            tP, HP, it, ib, hP, N_ATOMS, HP, H_DIM);
    }

    // segment-mean pool (sorted batch, no atomics), then out = pooled @ pool_w + b
    pool_seg_k<<<B_MOLS, blk, 0, stream>>>(hP, mrow, pooled);
    pool_mm2_k<<<dim3(10, B_MOLS), blk, 0, stream>>>(
        pooled, poolw, poolb, (float*)d_out);
}

// Round 11
// 1171.671 us; speedup vs baseline: 1.1030x; 1.1030x over previous
//
#include <hip/hip_runtime.h>
#include <math.h>

// SchNet forward, MI355X. Round 22 = r19 base + 2 subtiles per barrier pair
// (TK=64 per iteration).
// r21 evidence: async global_load_lds B REGRESSED (53.3->60.5us): compiler
// emits s_waitcnt vmcnt(0) before every s_barrier, so the prefetch drains
// inside barrier2 -- no overlap (guide's known ~20% barrier-drain stall).
// Reg-prefetch (r19) overlaps better: its waitcnt attaches to the consuming
// ds_write AFTER the next barrier. REVERTED.
// r19 budget: LDS ~28us, VALU ~27us, MFMA ~11us, measured 53.3 -> ~23us of
// barrier-synced stall over 19 chunk-iterations. Change: process TWO 32-k
// subtiles per barrier pair (10 iterations instead of 19). Each subtile
// keeps the exact r19 swizzle (s=row*4+((kq+(row>>1))&3), conflict-free;
// cross-subtile write aliasing is 2-way = free per m136). 24 MFMA per
// barrier pair. LDS 32KB (As[2][4096]+Bs[2][4096]) -> 5 blocks/CU,
// lb(256,5); VGPR ~70 < 102 cap. Grid stays 1600 blocks (r20 lesson:
// load balance dominates tile width). Numerics bit-identical.
// Stack: segment pool, batched tab GEMMs, packed bf16 hi/lo residual,
// 64x64 tiles, HP=608, XCD swizzle, CSR gather, pre-tiled fragment-major
// B weights, swizzled-A LDS, filter-table + lerp, split-K pool matmul
// (absmax 2.4e-4 vs 1.44e-3 budget).

#define N_ATOMS 10000
#define E_EDGES 64000
#define B_MOLS  128
#define H_DIM   600
#define HP      608            // padded leading dim (608*4B = 38 sectors)
#define G_DIM   50
#define L_LAYERS 6
#define M_TAB   1024
#define DMAX    8.67f
#define LOG2C   0.69314718056f

#define TM 64
#define TN 64

// B tile geometry: 64 cols x 32 k, fragment-major, hi plane then lo plane
#define BTILE 4096     // shorts per tile (2 planes x 2048)
#define NTILES_H 10    // col tiles for Nc=600
#define KT_BIG 19      // k tiles for K=608
#define KT_W1  2       // k tiles for K=64
#define BSTRIDE_BIG (NTILES_H * KT_BIG * BTILE)   // 778,240 shorts / layer
#define BSTRIDE_W1  (NTILES_H * KT_W1  * BTILE)   // 81,920 shorts / layer

typedef __attribute__((ext_vector_type(8))) short bf16x8;
typedef __attribute__((ext_vector_type(4))) float f32x4;

__device__ __forceinline__ float sspf(float x) {
    return fmaxf(x, 0.0f) + log1pf(expf(-fabsf(x))) - LOG2C;
}
__device__ __forceinline__ short f2bf(float x) {
    unsigned u = __float_as_uint(x);
    unsigned r = (u + 0x7FFF + ((u >> 16) & 1)) >> 16;   // RNE
    return (short)r;
}
__device__ __forceinline__ float bf2f(short h) {
    return __uint_as_float(((unsigned)(unsigned short)h) << 16);
}
__device__ __forceinline__ int packsplit(float x) {
    short hi = f2bf(x);
    short lo = f2bf(x - bf2f(hi));
    return ((int)hi << 16) | ((int)lo & 0xffff);
}
__device__ __forceinline__ float unpackf(int p) {
    float fh = __uint_as_float((unsigned)p & 0xffff0000u);
    float fl = __uint_as_float(((unsigned)p) << 16);
    return fh + fl;
}

// 8 packed ints -> hi-plane int4 + lo-plane int4 via v_perm_b32
// (verified bit-exact on HW in r14/r15)
__device__ __forceinline__ void unpack_perm(const int4& p0, const int4& p1,
                                            int4& hi, int4& lo)
{
    hi.x = (int)__builtin_amdgcn_perm((unsigned)p0.y, (unsigned)p0.x, 0x07060302u);
    hi.y = (int)__builtin_amdgcn_perm((unsigned)p0.w, (unsigned)p0.z, 0x07060302u);
    hi.z = (int)__builtin_amdgcn_perm((unsigned)p1.y, (unsigned)p1.x, 0x07060302u);
    hi.w = (int)__builtin_amdgcn_perm((unsigned)p1.w, (unsigned)p1.z, 0x07060302u);
    lo.x = (int)__builtin_amdgcn_perm((unsigned)p0.y, (unsigned)p0.x, 0x05040100u);
    lo.y = (int)__builtin_amdgcn_perm((unsigned)p0.w, (unsigned)p0.z, 0x05040100u);
    lo.z = (int)__builtin_amdgcn_perm((unsigned)p1.y, (unsigned)p1.x, 0x05040100u);
    lo.w = (int)__builtin_amdgcn_perm((unsigned)p1.w, (unsigned)p1.z, 0x05040100u);
}

// ---------------------------------------------------------------- MFMA GEMM
// outP = packsplit(op(A @ B + bias [+ unpack(outP)])). A: packed int [Ma][lda]
// (zero-padded cols). Bt: fragment-major tiles [nt][kt][hi2048|lo2048],
// zero-padded cols/k. K % 32 == 0. Output ld = HP, pad cols 0. 1D grid,
// XCD swizzle. Per iteration: stage TWO 32-k subtiles (r19 swizzle each),
// one barrier, 24 MFMA, one barrier. A rows clamped; OOB masked by epilogue.
template<bool BIAS, bool ACT, bool ACCUM>
__global__ __launch_bounds__(256, 5)
void gemm_mfma(const int* __restrict__ A, int lda,
               const short* __restrict__ Bt,
               const float* __restrict__ bias,
               int* __restrict__ outP,
               int Ma, int K, int Nc)
{
    const int NT = (Nc + TN - 1) / TN;
    const int f = blockIdx.x;
    const int xcd = f & 7, s = f >> 3;
    const int n0 = (s % NT) * TN;
    const int m0 = (xcd + 8 * (s / NT)) * TM;
    if (m0 >= Ma) return;
    const int KT = (K + 31) >> 5;

    __shared__ __align__(16) short As[2][4096];   // [plane][sub0|sub1]
    __shared__ __align__(16) short Bs[2][4096];   // [plane][sub0|sub1]

    const int tid = threadIdx.x;
    const int lane = tid & 63, wid = tid >> 6;
    const int wm = (wid >> 1) * 32, wn = (wid & 1) * 32;
    const int l15 = lane & 15, quad = lane >> 4;
    const int srow = tid >> 2;          // 0..63 (coalesced global map)
    const int skk  = (tid & 3) << 3;    // 0,8,16,24
    // swizzled A write index within a subtile (r19-proven)
    const int awidx = srow * 32 + ((((tid & 3) + (tid >> 3)) & 3) << 3);
    // swizzled A read offset (per-lane, rg-invariant)
    const int aoff  = l15 * 32 + (((quad + (l15 >> 1)) & 3) << 3);

    const int gm = min(m0 + srow, Ma - 1);
    const int*   aPtr = A + (size_t)gm * lda + skk;
    const short* bPtr = Bt + ((size_t)(n0 >> 6) * KT) * BTILE + tid * 8;

    f32x4 acc[2][2];
    #pragma unroll
    for (int i = 0; i < 2; ++i)
        #pragma unroll
        for (int j = 0; j < 2; ++j)
            acc[i][j] = (f32x4){0.f, 0.f, 0.f, 0.f};

    int4 ra0, ra1, ra2, ra3;
    bf16x8 rbh0, rbl0, rbh1, rbl1;

    // prologue: prefetch pair 0 (sub1 guarded)
    ra0 = *(const int4*)aPtr; ra1 = *(const int4*)(aPtr + 4);
    rbh0 = *(const bf16x8*)bPtr;
    rbl0 = *(const bf16x8*)(bPtr + 2048);
    if (32 < K) {
        ra2 = *(const int4*)(aPtr + 32); ra3 = *(const int4*)(aPtr + 36);
        rbh1 = *(const bf16x8*)(bPtr + 4096);
        rbl1 = *(const bf16x8*)(bPtr + 6144);
    }
    aPtr += 64; bPtr += 2 * BTILE;

    for (int k0 = 0; k0 < K; k0 += 64) {
        const bool has1 = (k0 + 32 < K);
        {
            int4 hi, lo;
            unpack_perm(ra0, ra1, hi, lo);
            *(int4*)&As[0][awidx] = hi;
            *(int4*)&As[1][awidx] = lo;
            unpack_perm(ra2, ra3, hi, lo);          // garbage if !has1; unread
            *(int4*)&As[0][2048 + awidx] = hi;
            *(int4*)&As[1][2048 + awidx] = lo;
            *(bf16x8*)&Bs[0][tid * 8]        = rbh0;
            *(bf16x8*)&Bs[1][tid * 8]        = rbl0;
            *(bf16x8*)&Bs[0][2048 + tid * 8] = rbh1;
            *(bf16x8*)&Bs[1][2048 + tid * 8] = rbl1;
        }

        // prefetch next pair (guarded; latency hides under barrier+MFMA)
        if (k0 + 64 < K) {
            ra0 = *(const int4*)aPtr; ra1 = *(const int4*)(aPtr + 4);
            rbh0 = *(const bf16x8*)bPtr;
            rbl0 = *(const bf16x8*)(bPtr + 2048);
            if (k0 + 96 < K) {
                ra2 = *(const int4*)(aPtr + 32); ra3 = *(const int4*)(aPtr + 36);
                rbh1 = *(const bf16x8*)(bPtr + 4096);
                rbl1 = *(const bf16x8*)(bPtr + 6144);
            }
            aPtr += 64; bPtr += 2 * BTILE;
        }

        __syncthreads();

        #pragma unroll
        for (int sb = 0; sb < 2; ++sb) {
            if (sb == 1 && !has1) break;
            const int so = sb * 2048;
            bf16x8 a_h[2], a_l[2], b_h[2], b_l[2];
            #pragma unroll
            for (int mi = 0; mi < 2; ++mi) {
                int ridx = so + ((wm >> 4) + mi) * 512 + aoff;
                a_h[mi] = *(const bf16x8*)&As[0][ridx];
                a_l[mi] = *(const bf16x8*)&As[1][ridx];
            }
            #pragma unroll
            for (int ni = 0; ni < 2; ++ni) {
                int ridx = so + ((wn >> 4) + ni) * 512 + lane * 8;
                b_h[ni] = *(const bf16x8*)&Bs[0][ridx];
                b_l[ni] = *(const bf16x8*)&Bs[1][ridx];
            }
            #pragma unroll
            for (int mi = 0; mi < 2; ++mi)
                #pragma unroll
                for (int ni = 0; ni < 2; ++ni) {
                    acc[mi][ni] = __builtin_amdgcn_mfma_f32_16x16x32_bf16(
                        a_h[mi], b_h[ni], acc[mi][ni], 0, 0, 0);
                    acc[mi][ni] = __builtin_amdgcn_mfma_f32_16x16x32_bf16(
                        a_h[mi], b_l[ni], acc[mi][ni], 0, 0, 0);
                    acc[mi][ni] = __builtin_amdgcn_mfma_f32_16x16x32_bf16(
                        a_l[mi], b_h[ni], acc[mi][ni], 0, 0, 0);
                }
        }
        __syncthreads();
    }

    #pragma unroll
    for (int mi = 0; mi < 2; ++mi) {
        #pragma unroll
        for (int r = 0; r < 4; ++r) {
            int row = m0 + wm + mi * 16 + quad * 4 + r;
            if (row >= Ma) continue;
            #pragma unroll
            for (int ni = 0; ni < 2; ++ni) {
                int col = n0 + wn + ni * 16 + l15;
                if (col >= HP) continue;
                size_t idx = (size_t)row * HP + col;
                float v = 0.0f;
                if (col < Nc) {
                    v = acc[mi][ni][r];
                    if constexpr (BIAS) v += bias[col];
                    if constexpr (ACT)  v = sspf(v);
                    if constexpr (ACCUM) v += unpackf(outP[idx]);
                }
                outP[idx] = packsplit(v);
            }
        }
    }
}

// Batched slab GEMM over all L layers stacked in M (1024 rows per layer).
// SHAREDA: A rows are (m % 1024). Same dual-subtile scheme.
template<bool SHAREDA, bool ACT>
__global__ __launch_bounds__(256, 5)
void gemm_tab(const int* __restrict__ A, int lda,
              const short* __restrict__ BtBase, size_t bstride,
              const float* __restrict__ biasBase,
              int* __restrict__ outP,
              int Ma, int K, int Nc)
{
    const int NT = (Nc + TN - 1) / TN;
    const int f = blockIdx.x;
    const int xcd = f & 7, s = f >> 3;
    const int n0 = (s % NT) * TN;
    const int m0 = (xcd + 8 * (s / NT)) * TM;
    if (m0 >= Ma) return;
    const int KT = (K + 31) >> 5;

    const int layer = m0 >> 10;                       // 1024 rows per layer
    const int arow0 = SHAREDA ? (m0 & 1023) : m0;
    const short* __restrict__ Bt = BtBase + (size_t)layer * bstride;
    const float* __restrict__ bias = biasBase + (size_t)layer * H_DIM;

    __shared__ __align__(16) short As[2][4096];
    __shared__ __align__(16) short Bs[2][4096];

    const int tid = threadIdx.x;
    const int lane = tid & 63, wid = tid >> 6;
    const int wm = (wid >> 1) * 32, wn = (wid & 1) * 32;
    const int l15 = lane & 15, quad = lane >> 4;
    const int srow = tid >> 2;
    const int skk  = (tid & 3) << 3;
    const int awidx = srow * 32 + ((((tid & 3) + (tid >> 3)) & 3) << 3);
    const int aoff  = l15 * 32 + (((quad + (l15 >> 1)) & 3) << 3);

    const int*   aPtr = A + (size_t)(arow0 + srow) * lda + skk;
    const short* bPtr = Bt + ((size_t)(n0 >> 6) * KT) * BTILE + tid * 8;

    f32x4 acc[2][2];
    #pragma unroll
    for (int i = 0; i < 2; ++i)
        #pragma unroll
        for (int j = 0; j < 2; ++j)
            acc[i][j] = (f32x4){0.f, 0.f, 0.f, 0.f};

    int4 ra0, ra1, ra2, ra3;
    bf16x8 rbh0, rbl0, rbh1, rbl1;

    ra0 = *(const int4*)aPtr; ra1 = *(const int4*)(aPtr + 4);
    rbh0 = *(const bf16x8*)bPtr;
    rbl0 = *(const bf16x8*)(bPtr + 2048);
    if (32 < K) {
        ra2 = *(const int4*)(aPtr + 32); ra3 = *(const int4*)(aPtr + 36);
        rbh1 = *(const bf16x8*)(bPtr + 4096);
        rbl1 = *(const bf16x8*)(bPtr + 6144);
    }
    aPtr += 64; bPtr += 2 * BTILE;

    for (int k0 = 0; k0 < K; k0 += 64) {
        const bool has1 = (k0 + 32 < K);
        {
            int4 hi, lo;
            unpack_perm(ra0, ra1, hi, lo);
            *(int4*)&As[0][awidx] = hi;
            *(int4*)&As[1][awidx] = lo;
            unpack_perm(ra2, ra3, hi, lo);
            *(int4*)&As[0][2048 + awidx] = hi;
            *(int4*)&As[1][2048 + awidx] = lo;
            *(bf16x8*)&Bs[0][tid * 8]        = rbh0;
            *(bf16x8*)&Bs[1][tid * 8]        = rbl0;
            *(bf16x8*)&Bs[0][2048 + tid * 8] = rbh1;
            *(bf16x8*)&Bs[1][2048 + tid * 8] = rbl1;
        }

        if (k0 + 64 < K) {
            ra0 = *(const int4*)aPtr; ra1 = *(const int4*)(aPtr + 4);
            rbh0 = *(const bf16x8*)bPtr;
            rbl0 = *(const bf16x8*)(bPtr + 2048);
            if (k0 + 96 < K) {
                ra2 = *(const int4*)(aPtr + 32); ra3 = *(const int4*)(aPtr + 36);
                rbh1 = *(const bf16x8*)(bPtr + 4096);
                rbl1 = *(const bf16x8*)(bPtr + 6144);
            }
            aPtr += 64; bPtr += 2 * BTILE;
        }

        __syncthreads();

        #pragma unroll
        for (int sb = 0; sb < 2; ++sb) {
            if (sb == 1 && !has1) break;
            const int so = sb * 2048;
            bf16x8 a_h[2], a_l[2], b_h[2], b_l[2];
            #pragma unroll
            for (int mi = 0; mi < 2; ++mi) {
                int ridx = so + ((wm >> 4) + mi) * 512 + aoff;
                a_h[mi] = *(const bf16x8*)&As[0][ridx];
                a_l[mi] = *(const bf16x8*)&As[1][ridx];
            }
            #pragma unroll
            for (int ni = 0; ni < 2; ++ni) {
                int ridx = so + ((wn >> 4) + ni) * 512 + lane * 8;
                b_h[ni] = *(const bf16x8*)&Bs[0][ridx];
                b_l[ni] = *(const bf16x8*)&Bs[1][ridx];
            }
            #pragma unroll
            for (int mi = 0; mi < 2; ++mi)
                #pragma unroll
                for (int ni = 0; ni < 2; ++ni) {
                    acc[mi][ni] = __builtin_amdgcn_mfma_f32_16x16x32_bf16(
                        a_h[mi], b_h[ni], acc[mi][ni], 0, 0, 0);
                    acc[mi][ni] = __builtin_amdgcn_mfma_f32_16x16x32_bf16(
                        a_h[mi], b_l[ni], acc[mi][ni], 0, 0, 0);
                    acc[mi][ni] = __builtin_amdgcn_mfma_f32_16x16x32_bf16(
                        a_l[mi], b_h[ni], acc[mi][ni], 0, 0, 0);
                }
        }
        __syncthreads();
    }

    #pragma unroll
    for (int mi = 0; mi < 2; ++mi) {
        #pragma unroll
        for (int r = 0; r < 4; ++r) {
            int row = m0 + wm + mi * 16 + quad * 4 + r;
            if (row >= Ma) continue;
            #pragma unroll
            for (int ni = 0; ni < 2; ++ni) {
                int col = n0 + wn + ni * 16 + l15;
                if (col >= HP) continue;
                float v = 0.0f;
                if (col < Nc) {
                    v = acc[mi][ni][r] + bias[col];
                    if constexpr (ACT) v = sspf(v);
                }
                outP[(size_t)row * HP + col] = packsplit(v);
            }
        }
    }
}

static inline dim3 mfma_grid(int Ma, int Nc) {
    int MB = (Ma + TM - 1) / TM;
    int NT = (Nc + TN - 1) / TN;
    int Ys = ((MB + 7) / 8) * 8;
    return dim3(Ys * NT);
}

// ------------------------------------------------- final pool matmul (tiny)
// pooled[128][600] @ pool_w[600][600] + b. 4-way K-split per column + LDS
// reduce: 1280 blocks (5/CU), serial chain 150 deep instead of 600.
__global__ __launch_bounds__(256)
void pool_mm2_k(const float* __restrict__ A, const float* __restrict__ W,
                const float* __restrict__ bias, float* __restrict__ out)
{
    __shared__ float arow[H_DIM];
    __shared__ float red[4][64];
    const int b = blockIdx.y;
    const int ct = blockIdx.x;             // 10 tiles of 64 cols
    const int t = threadIdx.x;
    const int ci = t & 63, kq = t >> 6;    // wave-uniform K quarter
    for (int k = t; k < H_DIM; k += 256)
        arow[k] = A[(size_t)b * H_DIM + k];
    __syncthreads();
    const int col = min(ct * 64 + ci, H_DIM - 1);   // clamp; store guarded
    const float* wp = W + (size_t)(kq * 150) * H_DIM + col;
    float s = 0.f;
    #pragma unroll 6
    for (int k = 0; k < 150; ++k)
        s = fmaf(arow[kq * 150 + k], wp[(size_t)k * H_DIM], s);
    red[kq][ci] = s;
    __syncthreads();
    if (kq == 0) {
        int c = ct * 64 + ci;
        if (c < H_DIM)
            out[(size_t)b * H_DIM + c] =
                red[0][ci] + red[1][ci] + red[2][ci] + red[3][ci] + bias[c];
    }
}

// ---------------------------------------------------------------- weight prep
// w1 -> fragment-major tiles: per layer [nt(10)][kt(2)][hi2048|lo2048]
__global__ __launch_bounds__(256)
void wts_w1_k(const float* __restrict__ w_all, short* __restrict__ w1t)
{
    __shared__ short th[64][65], tl[64][65];
    const int layer = blockIdx.z;
    const int nt = blockIdx.y;
    const float* w = w_all + (size_t)layer * G_DIM * H_DIM;
    short* outb = w1t + (size_t)layer * BSTRIDE_W1 + (size_t)nt * KT_W1 * BTILE;
    const int n0 = nt * 64;
    const int tid = threadIdx.x;
    #pragma unroll
    for (int p = 0; p < 4; ++p) {
        int k = p * 16 + (tid >> 4);
        int n4 = (tid & 15) << 2;
        float4 v = make_float4(0.f, 0.f, 0.f, 0.f);
        if (k < G_DIM && n0 + n4 + 3 < H_DIM)
            v = *(const float4*)(w + (size_t)k * H_DIM + n0 + n4);
        int px = packsplit(v.x), py = packsplit(v.y);
        int pz = packsplit(v.z), pw = packsplit(v.w);
        th[n4 + 0][k] = (short)(px >> 16); tl[n4 + 0][k] = (short)px;
        th[n4 + 1][k] = (short)(py >> 16); tl[n4 + 1][k] = (short)py;
        th[n4 + 2][k] = (short)(pz >> 16); tl[n4 + 2][k] = (short)pz;
        th[n4 + 3][k] = (short)(pw >> 16); tl[n4 + 3][k] = (short)pw;
    }
    __syncthreads();
    #pragma unroll
    for (int p = 0; p < 4; ++p) {
        int n = p * 16 + (tid >> 4);
        int k4 = (tid & 15) << 2;           // 0..60
        int kt = k4 >> 5, kk = k4 & 31;
        int idx = (n >> 4) * 512 + (kk >> 3) * 128 + (n & 15) * 8 + (kk & 7);
        short* tb = outb + (size_t)kt * BTILE;
        short4 sh = { th[n][k4], th[n][k4 + 1], th[n][k4 + 2], th[n][k4 + 3] };
        short4 sl = { tl[n][k4], tl[n][k4 + 1], tl[n][k4 + 2], tl[n][k4 + 3] };
        *(short4*)(tb + idx)        = sh;
        *(short4*)(tb + 2048 + idx) = sl;
    }
}

// big weights -> fragment-major tiles: per layer [nt(10)][kt(19)][hi|lo]
__global__ __launch_bounds__(256)
void wts_big_k(const float* __restrict__ w2, const float* __restrict__ l1,
               const float* __restrict__ l2, const float* __restrict__ iw,
               short* __restrict__ o2, short* __restrict__ o1,
               short* __restrict__ ol2, short* __restrict__ oi)
{
    __shared__ short th[64][65], tl[64][65];
    const int z = blockIdx.z, type = z / L_LAYERS, layer = z % L_LAYERS;
    const float* w; short* ob;
    if (type == 0)      { w = w2; ob = o2; }
    else if (type == 1) { w = l1; ob = o1; }
    else if (type == 2) { w = l2; ob = ol2; }
    else                { w = iw; ob = oi; }
    w  += (size_t)layer * H_DIM * H_DIM;
    ob += (size_t)layer * BSTRIDE_BIG;
    const int k0 = blockIdx.x * 64, nt = blockIdx.y, n0 = nt * 64;
    const int tid = threadIdx.x;
    #pragma unroll
    for (int p = 0; p < 4; ++p) {
        int k = p * 16 + (tid >> 4);
        int n4 = (tid & 15) << 2;
        float4 v = make_float4(0.f, 0.f, 0.f, 0.f);
        if (k0 + k < H_DIM && n0 + n4 + 3 < H_DIM)
            v = *(const float4*)(w + (size_t)(k0 + k) * H_DIM + n0 + n4);
        int px = packsplit(v.x), py = packsplit(v.y);
        int pz = packsplit(v.z), pw = packsplit(v.w);
        th[n4 + 0][k] = (short)(px >> 16); tl[n4 + 0][k] = (short)px;
        th[n4 + 1][k] = (short)(py >> 16); tl[n4 + 1][k] = (short)py;
        th[n4 + 2][k] = (short)(pz >> 16); tl[n4 + 2][k] = (short)pz;
        th[n4 + 3][k] = (short)(pw >> 16); tl[n4 + 3][k] = (short)pw;
    }
    __syncthreads();
    #pragma unroll
    for (int p = 0; p < 4; ++p) {
        int n = p * 16 + (tid >> 4);
        int k4 = (tid & 15) << 2;
        int kg = k0 + k4;
        if (kg >= KT_BIG * 32) continue;            // k0=576 block: k4<32 only
        int kt = kg >> 5, kk = kg & 31;
        int idx = (n >> 4) * 512 + (kk >> 3) * 128 + (n & 15) * 8 + (kk & 7);
        short* tb = ob + ((size_t)nt * KT_BIG + kt) * BTILE;
        short4 sh = { th[n][k4], th[n][k4 + 1], th[n][k4 + 2], th[n][k4 + 3] };
        short4 sl = { tl[n][k4], tl[n][k4 + 1], tl[n][k4 + 2], tl[n][k4 + 3] };
        *(short4*)(tb + idx)        = sh;
        *(short4*)(tb + 2048 + idx) = sl;
    }
}

// ---------------------------------------------------------------- helpers
__global__ __launch_bounds__(256)
void init_h_k(const int* __restrict__ z, const float* __restrict__ emb,
              int* __restrict__ hP)
{
    int t = blockIdx.x * 256 + threadIdx.x;
    const int QC = HP / 4;   // 152
    if (t >= N_ATOMS * QC) return;
    int i = t / QC;
    int q = (t - i * QC) << 2;
    size_t idx = (size_t)i * HP + q;
    if (q < H_DIM) {
        float4 v = *(const float4*)(emb + (size_t)z[i] * H_DIM + q);
        *(int4*)(hP + idx) = make_int4(packsplit(v.x), packsplit(v.y),
                                       packsplit(v.z), packsplit(v.w));
    } else {
        *(int4*)(hP + idx) = make_int4(0, 0, 0, 0);
    }
}

// per-edge record: {src*HP, i0*HP, a = C - f*C, b = f*C}
__global__ __launch_bounds__(256)
void edge_geom_k(const float* __restrict__ pos, const int* __restrict__ src,
                 const int* __restrict__ dst, float4* __restrict__ einfo)
{
    int e = blockIdx.x * 256 + threadIdx.x;
    if (e >= E_EDGES) return;
    int s = src[e], d0 = dst[e];
    float dx = pos[s * 3 + 0] - pos[d0 * 3 + 0];
    float dy = pos[s * 3 + 1] - pos[d0 * 3 + 1];
    float dz = pos[s * 3 + 2] - pos[d0 * 3 + 2];
    float dist = sqrtf(dx * dx + dy * dy + dz * dz + 1e-12f);
    float cc = 0.5f * (cosf(dist * 0.31415926535f) + 1.0f);
    float u = dist * ((float)(M_TAB - 1) / DMAX);
    u = fminf(fmaxf(u, 0.0f), (float)(M_TAB - 1) - 0.001f);
    int i0 = (int)u;
    float fc = (u - (float)i0) * cc;
    einfo[e] = make_float4(__int_as_float(s * HP),
                           __int_as_float(i0 * HP),
                           cc - fc, fc);
}

__global__ __launch_bounds__(256)
void rbf_tab_k(int* __restrict__ rtabP)
{
    int t = blockIdx.x * 256 + threadIdx.x;
    if (t >= M_TAB * 64) return;
    int i = t >> 6, g = t & 63;
    float v = 0.0f;
    if (g < G_DIM) {
        float dg  = (float)i * (DMAX / (float)(M_TAB - 1));
        float off = (float)g * (10.0f / 49.0f);
        float x = dg - off;
        const float coeff = -0.5f * (49.0f / 10.0f) * (49.0f / 10.0f);
        v = expf(coeff * x * x);
    }
    rtabP[t] = packsplit(v);
}

// ---------------------------------------------------------------- CSR build
__global__ __launch_bounds__(256)
void hist_k(const int* __restrict__ dst, int* __restrict__ deg)
{
    int e = blockIdx.x * 256 + threadIdx.x;
    if (e >= E_EDGES) return;
    atomicAdd(&deg[dst[e]], 1);
}

__global__ __launch_bounds__(1024)
void scan_k(const int* __restrict__ deg, int* __restrict__ rowptr)
{
    __shared__ int sums[1024];
    int tid = threadIdx.x;
    const int CHUNK = (N_ATOMS + 1023) / 1024;
    int base = tid * CHUNK;
    int local[16];
    int s = 0;
    #pragma unroll
    for (int c = 0; c < 16; ++c) {
        if (c >= CHUNK) break;
        int idx = base + c;
        local[c] = s;
        s += (idx < N_ATOMS) ? deg[idx] : 0;
    }
    sums[tid] = s;
    __syncthreads();
    for (int off = 1; off < 1024; off <<= 1) {
        int v = (tid >= off) ? sums[tid - off] : 0;
        __syncthreads();
        sums[tid] += v;
        __syncthreads();
    }
    int prefix = (tid > 0) ? sums[tid - 1] : 0;
    #pragma unroll
    for (int c = 0; c < 16; ++c) {
        if (c >= CHUNK) break;
        int idx = base + c;
        if (idx <= N_ATOMS) rowptr[idx] = prefix + local[c];
    }
    if (tid == 1023) rowptr[N_ATOMS] = sums[1023];
}

__global__ __launch_bounds__(256)
void fill_k(const int* __restrict__ dst, const float4* __restrict__ einfo,
            const int* __restrict__ rowptr, int* __restrict__ cursor,
            float4* __restrict__ esorted)
{
    int e = blockIdx.x * 256 + threadIdx.x;
    if (e >= E_EDGES) return;
    int d0 = dst[e];
    int pos = rowptr[d0] + atomicAdd(&cursor[d0], 1);
    esorted[pos] = einfo[e];
}

// molecule boundaries via binary search over the SORTED batch array
__global__ __launch_bounds__(256)
void bounds_k(const int* __restrict__ batch, int* __restrict__ mrow)
{
    int b = threadIdx.x;
    if (b > B_MOLS) return;
    int lo = 0, hi = N_ATOMS;
    while (lo < hi) {
        int mid = (lo + hi) >> 1;
        if (batch[mid] < b) lo = mid + 1; else hi = mid;
    }
    mrow[b] = lo;
}

// ---------------------------------------------------------------- gather
__device__ __forceinline__ void gacc(float4& acc, const int* yP, const int* wtP,
                                     const float4& ei, int q)
{
    int srow = __float_as_int(ei.x);
    int wrow = __float_as_int(ei.y);
    float a = ei.z, b = ei.w;
    int4 yv = *(const int4*)(yP + srow + q);
    int4 w0 = *(const int4*)(wtP + wrow + q);
    int4 w1 = *(const int4*)(wtP + wrow + HP + q);
    acc.x += unpackf(yv.x) * (a * unpackf(w0.x) + b * unpackf(w1.x));
    acc.y += unpackf(yv.y) * (a * unpackf(w0.y) + b * unpackf(w1.y));
    acc.z += unpackf(yv.z) * (a * unpackf(w0.z) + b * unpackf(w1.z));
    acc.w += unpackf(yv.w) * (a * unpackf(w0.w) + b * unpackf(w1.w));
}

__global__ __launch_bounds__(256)
void gather_k(const int* __restrict__ yP, const int* __restrict__ wtP,
              const int* __restrict__ rowptr, const float4* __restrict__ esorted,
              int* __restrict__ aggP)
{
    int t = blockIdx.x * 256 + threadIdx.x;
    const int QC = HP / 4;   // 152
    if (t >= N_ATOMS * QC) return;
    int i = t / QC;
    int q = (t - i * QC) << 2;
    size_t idx = (size_t)i * HP + q;
    if (q >= H_DIM) { *(int4*)(aggP + idx) = make_int4(0, 0, 0, 0); return; }
    int j0 = rowptr[i], j1 = rowptr[i + 1];
    float4 a0 = make_float4(0.f, 0.f, 0.f, 0.f);
    float4 a1 = make_float4(0.f, 0.f, 0.f, 0.f);
    int j = j0;
    for (; j + 2 <= j1; j += 2) {
        float4 e0 = esorted[j], e1 = esorted[j + 1];
        gacc(a0, yP, wtP, e0, q);
        gacc(a1, yP, wtP, e1, q);
    }
    if (j < j1) gacc(a0, yP, wtP, esorted[j], q);
    a0.x += a1.x; a0.y += a1.y; a0.z += a1.z; a0.w += a1.w;
    *(int4*)(aggP + idx) = make_int4(packsplit(a0.x), packsplit(a0.y),
                                     packsplit(a0.z), packsplit(a0.w));
}

// ---------------------------------------------------------------- pool (segment mean, no atomics)
__global__ __launch_bounds__(256)
void pool_seg_k(const int* __restrict__ hP, const int* __restrict__ mrow,
                float* __restrict__ pooled)
{
    int b = blockIdx.x;
    int t = threadIdx.x;
    if (t >= 150) return;               // cols 600..607 are pad
    int q = t << 2;
    int a = mrow[b], a1 = mrow[b + 1];
    float cnt = (float)(a1 - a);
    float4 s0 = make_float4(0.f, 0.f, 0.f, 0.f);
    float4 s1 = make_float4(0.f, 0.f, 0.f, 0.f);
    for (; a + 2 <= a1; a += 2) {
        int4 p0 = *(const int4*)(hP + (size_t)a * HP + q);
        int4 p1 = *(const int4*)(hP + (size_t)(a + 1) * HP + q);
        s0.x += unpackf(p0.x); s0.y += unpackf(p0.y);
        s0.z += unpackf(p0.z); s0.w += unpackf(p0.w);
        s1.x += unpackf(p1.x); s1.y += unpackf(p1.y);
        s1.z += unpackf(p1.z); s1.w += unpackf(p1.w);
    }
    if (a < a1) {
        int4 p0 = *(const int4*)(hP + (size_t)a * HP + q);
        s0.x += unpackf(p0.x); s0.y += unpackf(p0.y);
        s0.z += unpackf(p0.z); s0.w += unpackf(p0.w);
    }
    float inv = 1.0f / fmaxf(cnt, 1.0f);
    float4 o = make_float4((s0.x + s1.x) * inv, (s0.y + s1.y) * inv,
                           (s0.z + s1.z) * inv, (s0.w + s1.w) * inv);
    *(float4*)(pooled + (size_t)b * H_DIM + q) = o;
}

// ---------------------------------------------------------------- launch
extern "C" void kernel_launch(void* const* d_in, const int* in_sizes, int n_in,
                              void* d_out, int out_size, void* d_ws, size_t ws_size,
                              hipStream_t stream)
{
    const int*   z      = (const int*)  d_in[0];
    const float* pos    = (const float*)d_in[1];
    const int*   batch  = (const int*)  d_in[2];
    const int*   eidx   = (const int*)  d_in[3];
    const float* emb    = (const float*)d_in[4];
    const float* mlp_w1 = (const float*)d_in[5];
    const float* mlp_b1 = (const float*)d_in[6];
    const float* mlp_w2 = (const float*)d_in[7];
    const float* mlp_b2 = (const float*)d_in[8];
    const float* lin1_w = (const float*)d_in[9];
    const float* lin2_w = (const float*)d_in[10];
    const float* lin2_b = (const float*)d_in[11];
    const float* intw   = (const float*)d_in[12];
    const float* intb   = (const float*)d_in[13];
    const float* poolw  = (const float*)d_in[14];
    const float* poolb  = (const float*)d_in[15];

    float* ws = (float*)d_ws;
    const size_t NHP = (size_t)N_ATOMS * HP;       // 6,080,000
    const size_t TABALL = (size_t)L_LAYERS * M_TAB * HP;   // 3,735,552

    int*   hP    = (int*)ws;                       // NHP
    int*   y1P   = (int*)(ws + NHP);               // NHP; aliases tP, ttabA
    int*   tP    = y1P;
    int*   ttabA = y1P;                            // prep-time alias (3.7M <= NHP)
    int*   aggP  = (int*)(ws + 2 * NHP);           // NHP
    // aggP region aliases — ONLY prep-phase data dead before first gather:
    float4* einfo  = (float4*)aggP;                          // 256,000 f
    int*    deg    = (int*)((float*)aggP + 300000);          // 10,000
    int*    cursor = (int*)((float*)aggP + 310000);          // 10,000
    short*  w1t    = (short*)((float*)aggP + 400000);        // 491,520 shorts
    int*   wtabA = (int*)(ws + 3 * NHP);           // TABALL (persistent)
    int*   rtabP = (int*)(ws + 3 * NHP + TABALL);  // M_TAB*64 = 65,536
    // big weight tiles (4 types x 6 layers x 778,240 shorts)
    short* wtT   = (short*)(ws + 3 * NHP + TABALL + (size_t)M_TAB * 64);
    short* w2t = wtT;
    short* l1t = w2t + (size_t)L_LAYERS * BSTRIDE_BIG;
    short* l2t = l1t + (size_t)L_LAYERS * BSTRIDE_BIG;
    short* itt = l2t + (size_t)L_LAYERS * BSTRIDE_BIG;
    // persistent tail (NOT aliased): esorted, pooled, rowptr, mrow
    float*  tailF   = (float*)(itt + (size_t)L_LAYERS * BSTRIDE_BIG);
    float4* esorted = (float4*)tailF;                        // 256,000 f
    float*  pooled  = tailF + 256000;                        // 76,800 f
    int*    rowptr  = (int*)(tailF + 332800);                // 10,001
    int*    mrow    = rowptr + 10001;                        // 129

    const int* src = eidx;
    const int* dst = eidx + E_EDGES;

    const dim3 blk(256);
    const int QC = HP / 4;
    const dim3 gN   = mfma_grid(N_ATOMS, H_DIM);            // 1600
    const dim3 gTab = mfma_grid(L_LAYERS * M_TAB, H_DIM);   // 960

    // ---- one-time prep (einfo/deg/cursor/w1t alias aggP: dead before gather)
    edge_geom_k<<<(E_EDGES + 255) / 256, blk, 0, stream>>>(pos, src, dst, einfo);
    hipMemsetAsync(deg, 0, 2 * N_ATOMS * sizeof(int), stream);
    hist_k <<<(E_EDGES + 255) / 256, blk, 0, stream>>>(dst, deg);
    scan_k <<<1, 1024, 0, stream>>>(deg, rowptr);
    fill_k <<<(E_EDGES + 255) / 256, blk, 0, stream>>>(dst, einfo, rowptr, cursor, esorted);
    bounds_k <<<1, 256, 0, stream>>>(batch, mrow);
    init_h_k <<<(N_ATOMS * QC + 255) / 256, blk, 0, stream>>>(z, emb, hP);
    rbf_tab_k<<<(M_TAB * 64 + 255) / 256,   blk, 0, stream>>>(rtabP);
    wts_w1_k  <<<dim3(1, 10, 6),   blk, 0, stream>>>(mlp_w1, w1t);
    wts_big_k <<<dim3(10, 10, 24), blk, 0, stream>>>(
        mlp_w2, lin1_w, lin2_w, intw, w2t, l1t, l2t, itt);

    // ---- all 6 layers' filter tables in 2 batched slab GEMMs
    gemm_tab<true, true><<<gTab, blk, 0, stream>>>(
        rtabP, 64, w1t, (size_t)BSTRIDE_W1, mlp_b1,
        ttabA, L_LAYERS * M_TAB, 64, H_DIM);
    gemm_tab<false, false><<<gTab, blk, 0, stream>>>(
        ttabA, HP, w2t, (size_t)BSTRIDE_BIG, mlp_b2,
        wtabA, L_LAYERS * M_TAB, HP, H_DIM);

    for (int k = 0; k < L_LAYERS; ++k) {
        const float* l2b = lin2_b + (size_t)k * H_DIM;
        const float* ib  = intb   + (size_t)k * H_DIM;
        const short* l1 = l1t + (size_t)k * BSTRIDE_BIG;
        const short* l2 = l2t + (size_t)k * BSTRIDE_BIG;
        const short* it = itt + (size_t)k * BSTRIDE_BIG;
        const int*   wtP = wtabA + (size_t)k * M_TAB * HP;

        // y1P = packsplit(h @ lin1)
        gemm_mfma<false, false, false><<<gN, blk, 0, stream>>>(
            hP, HP, l1, nullptr, y1P, N_ATOMS, HP, H_DIM);
        // aggP = packsplit(CSR-gather(y1 * W(d) * C))
        gather_k<<<(N_ATOMS * QC + 255) / 256, blk, 0, stream>>>(
            y1P, wtP, rowptr, esorted, aggP);
        // tP = packsplit(ssp(agg @ lin2 + b))   (aliases y1P)
        gemm_mfma<true, true, false><<<gN, blk, 0, stream>>>(
            aggP, HP, l2, l2b, tP, N_ATOMS, HP, H_DIM);
        // hP = packsplit(unpack(hP) + t @ int_w + ib)
        gemm_mfma<true, false, true><<<gN, blk, 0, stream>>>(
            tP, HP, it, ib, hP, N_ATOMS, HP, H_DIM);
    }

    // segment-mean pool (sorted batch, no atomics), then out = pooled @ pool_w + b
    pool_seg_k<<<B_MOLS, blk, 0, stream>>>(hP, mrow, pooled);
    pool_mm2_k<<<dim3(10, B_MOLS), blk, 0, stream>>>(
        pooled, poolw, poolb, (float*)d_out);
}

// Round 12
// 1134.901 us; speedup vs baseline: 1.1387x; 1.0324x over previous
//
#include <hip/hip_runtime.h>
#include <math.h>

// SchNet forward, MI355X. Round 23 = r19 base + lgkmcnt-only barriers
// (counted-vmcnt pattern, T4-lite).
// r22 evidence: dual-subtile neutral (55.6 vs 53.3, occ 40->28%); seven
// structural variants all land 53-60us with no pipe >52% -> stall is
// exposed latency. Diagnosis: __syncthreads() = s_waitcnt vmcnt(0)
// lgkmcnt(0) + s_barrier. r19 issues the register prefetch right before
// barrier1 -> the mandatory vmcnt(0) drains the global loads there,
// covered by only ~50cyc of staging VALU. ~250cyc exposed x19 chunks =
// the 53us-vs-27us-floor gap. (r21's global_load_lds MUST drain at a
// barrier; VGPR-held loads need not -- only __syncthreads semantics
// force it.)
// Fix: replace __syncthreads with {asm lgkmcnt(0) w/ memory clobber;
// s_barrier; sched_barrier(0)} in both GEMMs. LDS ordering preserved
// (writes drained before barrier; asm fence + sched_barrier(0) pin both
// sides per rule #18). Global prefetch stays in flight across barriers;
// compiler's precise vmcnt(N) lands at next-iteration consumption,
// covered by this chunk's 8 ds_read_b128 + 12 MFMA. Everything else
// byte-identical to r19 (64x64 tiles, swizzled-A s=row*4+((kq+(row>>1))&3)
// conflict-free, pre-tiled identity B, 16KB LDS, lb(256,6), 1600 blocks).
// Stack: segment pool, batched tab GEMMs, packed bf16 hi/lo residual,
// HP=608, XCD swizzle, CSR gather, filter-table + lerp, split-K pool
// matmul (absmax 2.4e-4 vs 1.44e-3 budget).

#define N_ATOMS 10000
#define E_EDGES 64000
#define B_MOLS  128
#define H_DIM   600
#define HP      608            // padded leading dim (608*4B = 38 sectors)
#define G_DIM   50
#define L_LAYERS 6
#define M_TAB   1024
#define DMAX    8.67f
#define LOG2C   0.69314718056f

#define TM 64
#define TN 64
#define TK 32

// B tile geometry: 64 cols x 32 k, fragment-major, hi plane then lo plane
#define BTILE 4096     // shorts per tile (2 planes x 2048)
#define NTILES_H 10    // col tiles for Nc=600
#define KT_BIG 19      // k tiles for K=608
#define KT_W1  2       // k tiles for K=64
#define BSTRIDE_BIG (NTILES_H * KT_BIG * BTILE)   // 778,240 shorts / layer
#define BSTRIDE_W1  (NTILES_H * KT_W1  * BTILE)   // 81,920 shorts / layer

typedef __attribute__((ext_vector_type(8))) short bf16x8;
typedef __attribute__((ext_vector_type(4))) float f32x4;

__device__ __forceinline__ float sspf(float x) {
    return fmaxf(x, 0.0f) + log1pf(expf(-fabsf(x))) - LOG2C;
}
__device__ __forceinline__ short f2bf(float x) {
    unsigned u = __float_as_uint(x);
    unsigned r = (u + 0x7FFF + ((u >> 16) & 1)) >> 16;   // RNE
    return (short)r;
}
__device__ __forceinline__ float bf2f(short h) {
    return __uint_as_float(((unsigned)(unsigned short)h) << 16);
}
__device__ __forceinline__ int packsplit(float x) {
    short hi = f2bf(x);
    short lo = f2bf(x - bf2f(hi));
    return ((int)hi << 16) | ((int)lo & 0xffff);
}
__device__ __forceinline__ float unpackf(int p) {
    float fh = __uint_as_float((unsigned)p & 0xffff0000u);
    float fl = __uint_as_float(((unsigned)p) << 16);
    return fh + fl;
}

// Barrier that drains ONLY LDS ops (lgkmcnt), leaving global loads in
// flight across it. The asm memory clobber is a full compiler fence
// (prior ds_writes can't sink below, later ds_reads can't hoist above);
// sched_barrier(0) pins the region per guide rule #18. __syncthreads()
// would force vmcnt(0) and expose the prefetch latency every chunk.
__device__ __forceinline__ void block_sync_lds()
{
    asm volatile("s_waitcnt lgkmcnt(0)" ::: "memory");
    __builtin_amdgcn_s_barrier();
    __builtin_amdgcn_sched_barrier(0);
}

// 8 packed ints -> hi-plane int4 + lo-plane int4 via v_perm_b32
// (verified bit-exact on HW in r14/r15)
__device__ __forceinline__ void unpack_perm(const int4& p0, const int4& p1,
                                            int4& hi, int4& lo)
{
    hi.x = (int)__builtin_amdgcn_perm((unsigned)p0.y, (unsigned)p0.x, 0x07060302u);
    hi.y = (int)__builtin_amdgcn_perm((unsigned)p0.w, (unsigned)p0.z, 0x07060302u);
    hi.z = (int)__builtin_amdgcn_perm((unsigned)p1.y, (unsigned)p1.x, 0x07060302u);
    hi.w = (int)__builtin_amdgcn_perm((unsigned)p1.w, (unsigned)p1.z, 0x07060302u);
    lo.x = (int)__builtin_amdgcn_perm((unsigned)p0.y, (unsigned)p0.x, 0x05040100u);
    lo.y = (int)__builtin_amdgcn_perm((unsigned)p0.w, (unsigned)p0.z, 0x05040100u);
    lo.z = (int)__builtin_amdgcn_perm((unsigned)p1.y, (unsigned)p1.x, 0x05040100u);
    lo.w = (int)__builtin_amdgcn_perm((unsigned)p1.w, (unsigned)p1.z, 0x05040100u);
}

// ---------------------------------------------------------------- MFMA GEMM
// outP = packsplit(op(A @ B + bias [+ unpack(outP)])). A: packed int [Ma][lda]
// (zero-padded cols). Bt: fragment-major tiles [nt][kt][hi2048|lo2048],
// zero-padded cols/k. K % 32 == 0. Output ld = HP, pad cols 0. 1D grid,
// XCD swizzle. A staged via swizzled layout s(row,kq)=row*4+((kq+(row>>1))&3)
// (conflict-free both sides, r19-proven). B staging/reads identity
// lane-linear (conflict-free). lgkmcnt-only barriers keep the register
// prefetch in flight across them. A rows clamped; OOB masked by epilogue.
template<bool BIAS, bool ACT, bool ACCUM>
__global__ __launch_bounds__(256, 6)
void gemm_mfma(const int* __restrict__ A, int lda,
               const short* __restrict__ Bt,
               const float* __restrict__ bias,
               int* __restrict__ outP,
               int Ma, int K, int Nc)
{
    const int NT = (Nc + TN - 1) / TN;
    const int f = blockIdx.x;
    const int xcd = f & 7, s = f >> 3;
    const int n0 = (s % NT) * TN;
    const int m0 = (xcd + 8 * (s / NT)) * TM;
    if (m0 >= Ma) return;
    const int KT = (K + 31) >> 5;

    __shared__ __align__(16) short As[2][2048];
    __shared__ __align__(16) short Bs[2][2048];

    const int tid = threadIdx.x;
    const int lane = tid & 63, wid = tid >> 6;
    const int wm = (wid >> 1) * 32, wn = (wid & 1) * 32;
    const int l15 = lane & 15, quad = lane >> 4;
    const int srow = tid >> 2;          // 0..63 (coalesced global map)
    const int skk  = (tid & 3) << 3;    // 0,8,16,24
    // swizzled A write index: s = srow*4 + ((kq + (srow>>1)) & 3), shorts = s*8
    const int awidx = srow * 32 + ((((tid & 3) + (tid >> 3)) & 3) << 3);
    // swizzled A read offset (per-lane, rg-invariant)
    const int aoff  = l15 * 32 + (((quad + (l15 >> 1)) & 3) << 3);

    const int gm = min(m0 + srow, Ma - 1);
    const int*   aPtr = A + (size_t)gm * lda + skk;
    const short* bPtr = Bt + ((size_t)(n0 >> 6) * KT) * BTILE + tid * 8;

    f32x4 acc[2][2];
    #pragma unroll
    for (int i = 0; i < 2; ++i)
        #pragma unroll
        for (int j = 0; j < 2; ++j)
            acc[i][j] = (f32x4){0.f, 0.f, 0.f, 0.f};

    int4 ra0, ra1;
    bf16x8 rbh, rbl;

    // prefetch chunk 0
    ra0 = *(const int4*)aPtr; ra1 = *(const int4*)(aPtr + 4);
    rbh = *(const bf16x8*)bPtr;
    rbl = *(const bf16x8*)(bPtr + 2048);
    aPtr += TK; bPtr += BTILE;

    for (int k0 = 0; k0 < K; k0 += TK) {
        {
            int4 hi, lo;
            unpack_perm(ra0, ra1, hi, lo);
            *(int4*)&As[0][awidx] = hi;
            *(int4*)&As[1][awidx] = lo;
            *(bf16x8*)&Bs[0][tid * 8] = rbh;
            *(bf16x8*)&Bs[1][tid * 8] = rbl;
        }
        block_sync_lds();   // lgkmcnt only; prefetch below stays in flight

        if (k0 + TK < K) {
            ra0 = *(const int4*)aPtr; ra1 = *(const int4*)(aPtr + 4);
            rbh = *(const bf16x8*)bPtr;
            rbl = *(const bf16x8*)(bPtr + 2048);
            aPtr += TK; bPtr += BTILE;
        }

        bf16x8 a_h[2], a_l[2], b_h[2], b_l[2];
        #pragma unroll
        for (int mi = 0; mi < 2; ++mi) {
            int ridx = ((wm >> 4) + mi) * 512 + aoff;
            a_h[mi] = *(const bf16x8*)&As[0][ridx];
            a_l[mi] = *(const bf16x8*)&As[1][ridx];
        }
        #pragma unroll
        for (int ni = 0; ni < 2; ++ni) {
            int ridx = ((wn >> 4) + ni) * 512 + lane * 8;
            b_h[ni] = *(const bf16x8*)&Bs[0][ridx];
            b_l[ni] = *(const bf16x8*)&Bs[1][ridx];
        }

        #pragma unroll
        for (int mi = 0; mi < 2; ++mi)
            #pragma unroll
            for (int ni = 0; ni < 2; ++ni) {
                acc[mi][ni] = __builtin_amdgcn_mfma_f32_16x16x32_bf16(
                    a_h[mi], b_h[ni], acc[mi][ni], 0, 0, 0);
                acc[mi][ni] = __builtin_amdgcn_mfma_f32_16x16x32_bf16(
                    a_h[mi], b_l[ni], acc[mi][ni], 0, 0, 0);
                acc[mi][ni] = __builtin_amdgcn_mfma_f32_16x16x32_bf16(
                    a_l[mi], b_h[ni], acc[mi][ni], 0, 0, 0);
            }
        block_sync_lds();   // reads already drained by MFMA deps
    }

    #pragma unroll
    for (int mi = 0; mi < 2; ++mi) {
        #pragma unroll
        for (int r = 0; r < 4; ++r) {
            int row = m0 + wm + mi * 16 + quad * 4 + r;
            if (row >= Ma) continue;
            #pragma unroll
            for (int ni = 0; ni < 2; ++ni) {
                int col = n0 + wn + ni * 16 + l15;
                if (col >= HP) continue;
                size_t idx = (size_t)row * HP + col;
                float v = 0.0f;
                if (col < Nc) {
                    v = acc[mi][ni][r];
                    if constexpr (BIAS) v += bias[col];
                    if constexpr (ACT)  v = sspf(v);
                    if constexpr (ACCUM) v += unpackf(outP[idx]);
                }
                outP[idx] = packsplit(v);
            }
        }
    }
}

// Batched slab GEMM over all L layers stacked in M (1024 rows per layer).
// SHAREDA: A rows are (m % 1024). Same swizzled-A + tiled-B + raw-barrier.
template<bool SHAREDA, bool ACT>
__global__ __launch_bounds__(256, 6)
void gemm_tab(const int* __restrict__ A, int lda,
              const short* __restrict__ BtBase, size_t bstride,
              const float* __restrict__ biasBase,
              int* __restrict__ outP,
              int Ma, int K, int Nc)
{
    const int NT = (Nc + TN - 1) / TN;
    const int f = blockIdx.x;
    const int xcd = f & 7, s = f >> 3;
    const int n0 = (s % NT) * TN;
    const int m0 = (xcd + 8 * (s / NT)) * TM;
    if (m0 >= Ma) return;
    const int KT = (K + 31) >> 5;

    const int layer = m0 >> 10;                       // 1024 rows per layer
    const int arow0 = SHAREDA ? (m0 & 1023) : m0;
    const short* __restrict__ Bt = BtBase + (size_t)layer * bstride;
    const float* __restrict__ bias = biasBase + (size_t)layer * H_DIM;

    __shared__ __align__(16) short As[2][2048];
    __shared__ __align__(16) short Bs[2][2048];

    const int tid = threadIdx.x;
    const int lane = tid & 63, wid = tid >> 6;
    const int wm = (wid >> 1) * 32, wn = (wid & 1) * 32;
    const int l15 = lane & 15, quad = lane >> 4;
    const int srow = tid >> 2;
    const int skk  = (tid & 3) << 3;
    const int awidx = srow * 32 + ((((tid & 3) + (tid >> 3)) & 3) << 3);
    const int aoff  = l15 * 32 + (((quad + (l15 >> 1)) & 3) << 3);

    const int*   aPtr = A + (size_t)(arow0 + srow) * lda + skk;
    const short* bPtr = Bt + ((size_t)(n0 >> 6) * KT) * BTILE + tid * 8;

    f32x4 acc[2][2];
    #pragma unroll
    for (int i = 0; i < 2; ++i)
        #pragma unroll
        for (int j = 0; j < 2; ++j)
            acc[i][j] = (f32x4){0.f, 0.f, 0.f, 0.f};

    int4 ra0, ra1;
    bf16x8 rbh, rbl;

    ra0 = *(const int4*)aPtr; ra1 = *(const int4*)(aPtr + 4);
    rbh = *(const bf16x8*)bPtr;
    rbl = *(const bf16x8*)(bPtr + 2048);
    aPtr += TK; bPtr += BTILE;

    for (int k0 = 0; k0 < K; k0 += TK) {
        {
            int4 hi, lo;
            unpack_perm(ra0, ra1, hi, lo);
            *(int4*)&As[0][awidx] = hi;
            *(int4*)&As[1][awidx] = lo;
            *(bf16x8*)&Bs[0][tid * 8] = rbh;
            *(bf16x8*)&Bs[1][tid * 8] = rbl;
        }
        block_sync_lds();

        if (k0 + TK < K) {
            ra0 = *(const int4*)aPtr; ra1 = *(const int4*)(aPtr + 4);
            rbh = *(const bf16x8*)bPtr;
            rbl = *(const bf16x8*)(bPtr + 2048);
            aPtr += TK; bPtr += BTILE;
        }

        bf16x8 a_h[2], a_l[2], b_h[2], b_l[2];
        #pragma unroll
        for (int mi = 0; mi < 2; ++mi) {
            int ridx = ((wm >> 4) + mi) * 512 + aoff;
            a_h[mi] = *(const bf16x8*)&As[0][ridx];
            a_l[mi] = *(const bf16x8*)&As[1][ridx];
        }
        #pragma unroll
        for (int ni = 0; ni < 2; ++ni) {
            int ridx = ((wn >> 4) + ni) * 512 + lane * 8;
            b_h[ni] = *(const bf16x8*)&Bs[0][ridx];
            b_l[ni] = *(const bf16x8*)&Bs[1][ridx];
        }
        #pragma unroll
        for (int mi = 0; mi < 2; ++mi)
            #pragma unroll
            for (int ni = 0; ni < 2; ++ni) {
                acc[mi][ni] = __builtin_amdgcn_mfma_f32_16x16x32_bf16(
                    a_h[mi], b_h[ni], acc[mi][ni], 0, 0, 0);
                acc[mi][ni] = __builtin_amdgcn_mfma_f32_16x16x32_bf16(
                    a_h[mi], b_l[ni], acc[mi][ni], 0, 0, 0);
                acc[mi][ni] = __builtin_amdgcn_mfma_f32_16x16x32_bf16(
                    a_l[mi], b_h[ni], acc[mi][ni], 0, 0, 0);
            }
        block_sync_lds();
    }

    #pragma unroll
    for (int mi = 0; mi < 2; ++mi) {
        #pragma unroll
        for (int r = 0; r < 4; ++r) {
            int row = m0 + wm + mi * 16 + quad * 4 + r;
            if (row >= Ma) continue;
            #pragma unroll
            for (int ni = 0; ni < 2; ++ni) {
                int col = n0 + wn + ni * 16 + l15;
                if (col >= HP) continue;
                float v = 0.0f;
                if (col < Nc) {
                    v = acc[mi][ni][r] + bias[col];
                    if constexpr (ACT) v = sspf(v);
                }
                outP[(size_t)row * HP + col] = packsplit(v);
            }
        }
    }
}

static inline dim3 mfma_grid(int Ma, int Nc) {
    int MB = (Ma + TM - 1) / TM;
    int NT = (Nc + TN - 1) / TN;
    int Ys = ((MB + 7) / 8) * 8;
    return dim3(Ys * NT);
}

// ------------------------------------------------- final pool matmul (tiny)
// pooled[128][600] @ pool_w[600][600] + b. 4-way K-split per column + LDS
// reduce: 1280 blocks (5/CU), serial chain 150 deep instead of 600.
__global__ __launch_bounds__(256)
void pool_mm2_k(const float* __restrict__ A, const float* __restrict__ W,
                const float* __restrict__ bias, float* __restrict__ out)
{
    __shared__ float arow[H_DIM];
    __shared__ float red[4][64];
    const int b = blockIdx.y;
    const int ct = blockIdx.x;             // 10 tiles of 64 cols
    const int t = threadIdx.x;
    const int ci = t & 63, kq = t >> 6;    // wave-uniform K quarter
    for (int k = t; k < H_DIM; k += 256)
        arow[k] = A[(size_t)b * H_DIM + k];
    __syncthreads();
    const int col = min(ct * 64 + ci, H_DIM - 1);   // clamp; store guarded
    const float* wp = W + (size_t)(kq * 150) * H_DIM + col;
    float s = 0.f;
    #pragma unroll 6
    for (int k = 0; k < 150; ++k)
        s = fmaf(arow[kq * 150 + k], wp[(size_t)k * H_DIM], s);
    red[kq][ci] = s;
    __syncthreads();
    if (kq == 0) {
        int c = ct * 64 + ci;
        if (c < H_DIM)
            out[(size_t)b * H_DIM + c] =
                red[0][ci] + red[1][ci] + red[2][ci] + red[3][ci] + bias[c];
    }
}

// ---------------------------------------------------------------- weight prep
// w1 -> fragment-major tiles: per layer [nt(10)][kt(2)][hi2048|lo2048]
__global__ __launch_bounds__(256)
void wts_w1_k(const float* __restrict__ w_all, short* __restrict__ w1t)
{
    __shared__ short th[64][65], tl[64][65];
    const int layer = blockIdx.z;
    const int nt = blockIdx.y;
    const float* w = w_all + (size_t)layer * G_DIM * H_DIM;
    short* outb = w1t + (size_t)layer * BSTRIDE_W1 + (size_t)nt * KT_W1 * BTILE;
    const int n0 = nt * 64;
    const int tid = threadIdx.x;
    #pragma unroll
    for (int p = 0; p < 4; ++p) {
        int k = p * 16 + (tid >> 4);
        int n4 = (tid & 15) << 2;
        float4 v = make_float4(0.f, 0.f, 0.f, 0.f);
        if (k < G_DIM && n0 + n4 + 3 < H_DIM)
            v = *(const float4*)(w + (size_t)k * H_DIM + n0 + n4);
        int px = packsplit(v.x), py = packsplit(v.y);
        int pz = packsplit(v.z), pw = packsplit(v.w);
        th[n4 + 0][k] = (short)(px >> 16); tl[n4 + 0][k] = (short)px;
        th[n4 + 1][k] = (short)(py >> 16); tl[n4 + 1][k] = (short)py;
        th[n4 + 2][k] = (short)(pz >> 16); tl[n4 + 2][k] = (short)pz;
        th[n4 + 3][k] = (short)(pw >> 16); tl[n4 + 3][k] = (short)pw;
    }
    __syncthreads();
    #pragma unroll
    for (int p = 0; p < 4; ++p) {
        int n = p * 16 + (tid >> 4);
        int k4 = (tid & 15) << 2;           // 0..60
        int kt = k4 >> 5, kk = k4 & 31;
        int idx = (n >> 4) * 512 + (kk >> 3) * 128 + (n & 15) * 8 + (kk & 7);
        short* tb = outb + (size_t)kt * BTILE;
        short4 sh = { th[n][k4], th[n][k4 + 1], th[n][k4 + 2], th[n][k4 + 3] };
        short4 sl = { tl[n][k4], tl[n][k4 + 1], tl[n][k4 + 2], tl[n][k4 + 3] };
        *(short4*)(tb + idx)        = sh;
        *(short4*)(tb + 2048 + idx) = sl;
    }
}

// big weights -> fragment-major tiles: per layer [nt(10)][kt(19)][hi|lo]
__global__ __launch_bounds__(256)
void wts_big_k(const float* __restrict__ w2, const float* __restrict__ l1,
               const float* __restrict__ l2, const float* __restrict__ iw,
               short* __restrict__ o2, short* __restrict__ o1,
               short* __restrict__ ol2, short* __restrict__ oi)
{
    __shared__ short th[64][65], tl[64][65];
    const int z = blockIdx.z, type = z / L_LAYERS, layer = z % L_LAYERS;
    const float* w; short* ob;
    if (type == 0)      { w = w2; ob = o2; }
    else if (type == 1) { w = l1; ob = o1; }
    else if (type == 2) { w = l2; ob = ol2; }
    else                { w = iw; ob = oi; }
    w  += (size_t)layer * H_DIM * H_DIM;
    ob += (size_t)layer * BSTRIDE_BIG;
    const int k0 = blockIdx.x * 64, nt = blockIdx.y, n0 = nt * 64;
    const int tid = threadIdx.x;
    #pragma unroll
    for (int p = 0; p < 4; ++p) {
        int k = p * 16 + (tid >> 4);
        int n4 = (tid & 15) << 2;
        float4 v = make_float4(0.f, 0.f, 0.f, 0.f);
        if (k0 + k < H_DIM && n0 + n4 + 3 < H_DIM)
            v = *(const float4*)(w + (size_t)(k0 + k) * H_DIM + n0 + n4);
        int px = packsplit(v.x), py = packsplit(v.y);
        int pz = packsplit(v.z), pw = packsplit(v.w);
        th[n4 + 0][k] = (short)(px >> 16); tl[n4 + 0][k] = (short)px;
        th[n4 + 1][k] = (short)(py >> 16); tl[n4 + 1][k] = (short)py;
        th[n4 + 2][k] = (short)(pz >> 16); tl[n4 + 2][k] = (short)pz;
        th[n4 + 3][k] = (short)(pw >> 16); tl[n4 + 3][k] = (short)pw;
    }
    __syncthreads();
    #pragma unroll
    for (int p = 0; p < 4; ++p) {
        int n = p * 16 + (tid >> 4);
        int k4 = (tid & 15) << 2;
        int kg = k0 + k4;
        if (kg >= KT_BIG * 32) continue;            // k0=576 block: k4<32 only
        int kt = kg >> 5, kk = kg & 31;
        int idx = (n >> 4) * 512 + (kk >> 3) * 128 + (n & 15) * 8 + (kk & 7);
        short* tb = ob + ((size_t)nt * KT_BIG + kt) * BTILE;
        short4 sh = { th[n][k4], th[n][k4 + 1], th[n][k4 + 2], th[n][k4 + 3] };
        short4 sl = { tl[n][k4], tl[n][k4 + 1], tl[n][k4 + 2], tl[n][k4 + 3] };
        *(short4*)(tb + idx)        = sh;
        *(short4*)(tb + 2048 + idx) = sl;
    }
}

// ---------------------------------------------------------------- helpers
__global__ __launch_bounds__(256)
void init_h_k(const int* __restrict__ z, const float* __restrict__ emb,
              int* __restrict__ hP)
{
    int t = blockIdx.x * 256 + threadIdx.x;
    const int QC = HP / 4;   // 152
    if (t >= N_ATOMS * QC) return;
    int i = t / QC;
    int q = (t - i * QC) << 2;
    size_t idx = (size_t)i * HP + q;
    if (q < H_DIM) {
        float4 v = *(const float4*)(emb + (size_t)z[i] * H_DIM + q);
        *(int4*)(hP + idx) = make_int4(packsplit(v.x), packsplit(v.y),
                                       packsplit(v.z), packsplit(v.w));
    } else {
        *(int4*)(hP + idx) = make_int4(0, 0, 0, 0);
    }
}

// per-edge record: {src*HP, i0*HP, a = C - f*C, b = f*C}
__global__ __launch_bounds__(256)
void edge_geom_k(const float* __restrict__ pos, const int* __restrict__ src,
                 const int* __restrict__ dst, float4* __restrict__ einfo)
{
    int e = blockIdx.x * 256 + threadIdx.x;
    if (e >= E_EDGES) return;
    int s = src[e], d0 = dst[e];
    float dx = pos[s * 3 + 0] - pos[d0 * 3 + 0];
    float dy = pos[s * 3 + 1] - pos[d0 * 3 + 1];
    float dz = pos[s * 3 + 2] - pos[d0 * 3 + 2];
    float dist = sqrtf(dx * dx + dy * dy + dz * dz + 1e-12f);
    float cc = 0.5f * (cosf(dist * 0.31415926535f) + 1.0f);
    float u = dist * ((float)(M_TAB - 1) / DMAX);
    u = fminf(fmaxf(u, 0.0f), (float)(M_TAB - 1) - 0.001f);
    int i0 = (int)u;
    float fc = (u - (float)i0) * cc;
    einfo[e] = make_float4(__int_as_float(s * HP),
                           __int_as_float(i0 * HP),
                           cc - fc, fc);
}

__global__ __launch_bounds__(256)
void rbf_tab_k(int* __restrict__ rtabP)
{
    int t = blockIdx.x * 256 + threadIdx.x;
    if (t >= M_TAB * 64) return;
    int i = t >> 6, g = t & 63;
    float v = 0.0f;
    if (g < G_DIM) {
        float dg  = (float)i * (DMAX / (float)(M_TAB - 1));
        float off = (float)g * (10.0f / 49.0f);
        float x = dg - off;
        const float coeff = -0.5f * (49.0f / 10.0f) * (49.0f / 10.0f);
        v = expf(coeff * x * x);
    }
    rtabP[t] = packsplit(v);
}

// ---------------------------------------------------------------- CSR build
__global__ __launch_bounds__(256)
void hist_k(const int* __restrict__ dst, int* __restrict__ deg)
{
    int e = blockIdx.x * 256 + threadIdx.x;
    if (e >= E_EDGES) return;
    atomicAdd(&deg[dst[e]], 1);
}

__global__ __launch_bounds__(1024)
void scan_k(const int* __restrict__ deg, int* __restrict__ rowptr)
{
    __shared__ int sums[1024];
    int tid = threadIdx.x;
    const int CHUNK = (N_ATOMS + 1023) / 1024;
    int base = tid * CHUNK;
    int local[16];
    int s = 0;
    #pragma unroll
    for (int c = 0; c < 16; ++c) {
        if (c >= CHUNK) break;
        int idx = base + c;
        local[c] = s;
        s += (idx < N_ATOMS) ? deg[idx] : 0;
    }
    sums[tid] = s;
    __syncthreads();
    for (int off = 1; off < 1024; off <<= 1) {
        int v = (tid >= off) ? sums[tid - off] : 0;
        __syncthreads();
        sums[tid] += v;
        __syncthreads();
    }
    int prefix = (tid > 0) ? sums[tid - 1] : 0;
    #pragma unroll
    for (int c = 0; c < 16; ++c) {
        if (c >= CHUNK) break;
        int idx = base + c;
        if (idx <= N_ATOMS) rowptr[idx] = prefix + local[c];
    }
    if (tid == 1023) rowptr[N_ATOMS] = sums[1023];
}

__global__ __launch_bounds__(256)
void fill_k(const int* __restrict__ dst, const float4* __restrict__ einfo,
            const int* __restrict__ rowptr, int* __restrict__ cursor,
            float4* __restrict__ esorted)
{
    int e = blockIdx.x * 256 + threadIdx.x;
    if (e >= E_EDGES) return;
    int d0 = dst[e];
    int pos = rowptr[d0] + atomicAdd(&cursor[d0], 1);
    esorted[pos] = einfo[e];
}

// molecule boundaries via binary search over the SORTED batch array
__global__ __launch_bounds__(256)
void bounds_k(const int* __restrict__ batch, int* __restrict__ mrow)
{
    int b = threadIdx.x;
    if (b > B_MOLS) return;
    int lo = 0, hi = N_ATOMS;
    while (lo < hi) {
        int mid = (lo + hi) >> 1;
        if (batch[mid] < b) lo = mid + 1; else hi = mid;
    }
    mrow[b] = lo;
}

// ---------------------------------------------------------------- gather
__device__ __forceinline__ void gacc(float4& acc, const int* yP, const int* wtP,
                                     const float4& ei, int q)
{
    int srow = __float_as_int(ei.x);
    int wrow = __float_as_int(ei.y);
    float a = ei.z, b = ei.w;
    int4 yv = *(const int4*)(yP + srow + q);
    int4 w0 = *(const int4*)(wtP + wrow + q);
    int4 w1 = *(const int4*)(wtP + wrow + HP + q);
    acc.x += unpackf(yv.x) * (a * unpackf(w0.x) + b * unpackf(w1.x));
    acc.y += unpackf(yv.y) * (a * unpackf(w0.y) + b * unpackf(w1.y));
    acc.z += unpackf(yv.z) * (a * unpackf(w0.z) + b * unpackf(w1.z));
    acc.w += unpackf(yv.w) * (a * unpackf(w0.w) + b * unpackf(w1.w));
}

__global__ __launch_bounds__(256)
void gather_k(const int* __restrict__ yP, const int* __restrict__ wtP,
              const int* __restrict__ rowptr, const float4* __restrict__ esorted,
              int* __restrict__ aggP)
{
    int t = blockIdx.x * 256 + threadIdx.x;
    const int QC = HP / 4;   // 152
    if (t >= N_ATOMS * QC) return;
    int i = t / QC;
    int q = (t - i * QC) << 2;
    size_t idx = (size_t)i * HP + q;
    if (q >= H_DIM) { *(int4*)(aggP + idx) = make_int4(0, 0, 0, 0); return; }
    int j0 = rowptr[i], j1 = rowptr[i + 1];
    float4 a0 = make_float4(0.f, 0.f, 0.f, 0.f);
    float4 a1 = make_float4(0.f, 0.f, 0.f, 0.f);
    int j = j0;
    for (; j + 2 <= j1; j += 2) {
        float4 e0 = esorted[j], e1 = esorted[j + 1];
        gacc(a0, yP, wtP, e0, q);
        gacc(a1, yP, wtP, e1, q);
    }
    if (j < j1) gacc(a0, yP, wtP, esorted[j], q);
    a0.x += a1.x; a0.y += a1.y; a0.z += a1.z; a0.w += a1.w;
    *(int4*)(aggP + idx) = make_int4(packsplit(a0.x), packsplit(a0.y),
                                     packsplit(a0.z), packsplit(a0.w));
}

// ---------------------------------------------------------------- pool (segment mean, no atomics)
__global__ __launch_bounds__(256)
void pool_seg_k(const int* __restrict__ hP, const int* __restrict__ mrow,
                float* __restrict__ pooled)
{
    int b = blockIdx.x;
    int t = threadIdx.x;
    if (t >= 150) return;               // cols 600..607 are pad
    int q = t << 2;
    int a = mrow[b], a1 = mrow[b + 1];
    float cnt = (float)(a1 - a);
    float4 s0 = make_float4(0.f, 0.f, 0.f, 0.f);
    float4 s1 = make_float4(0.f, 0.f, 0.f, 0.f);
    for (; a + 2 <= a1; a += 2) {
        int4 p0 = *(const int4*)(hP + (size_t)a * HP + q);
        int4 p1 = *(const int4*)(hP + (size_t)(a + 1) * HP + q);
        s0.x += unpackf(p0.x); s0.y += unpackf(p0.y);
        s0.z += unpackf(p0.z); s0.w += unpackf(p0.w);
        s1.x += unpackf(p1.x); s1.y += unpackf(p1.y);
        s1.z += unpackf(p1.z); s1.w += unpackf(p1.w);
    }
    if (a < a1) {
        int4 p0 = *(const int4*)(hP + (size_t)a * HP + q);
        s0.x += unpackf(p0.x); s0.y += unpackf(p0.y);
        s0.z += unpackf(p0.z); s0.w += unpackf(p0.w);
    }
    float inv = 1.0f / fmaxf(cnt, 1.0f);
    float4 o = make_float4((s0.x + s1.x) * inv, (s0.y + s1.y) * inv,
                           (s0.z + s1.z) * inv, (s0.w + s1.w) * inv);
    *(float4*)(pooled + (size_t)b * H_DIM + q) = o;
}

// ---------------------------------------------------------------- launch
extern "C" void kernel_launch(void* const* d_in, const int* in_sizes, int n_in,
                              void* d_out, int out_size, void* d_ws, size_t ws_size,
                              hipStream_t stream)
{
    const int*   z      = (const int*)  d_in[0];
    const float* pos    = (const float*)d_in[1];
    const int*   batch  = (const int*)  d_in[2];
    const int*   eidx   = (const int*)  d_in[3];
    const float* emb    = (const float*)d_in[4];
    const float* mlp_w1 = (const float*)d_in[5];
    const float* mlp_b1 = (const float*)d_in[6];
    const float* mlp_w2 = (const float*)d_in[7];
    const float* mlp_b2 = (const float*)d_in[8];
    const float* lin1_w = (const float*)d_in[9];
    const float* lin2_w = (const float*)d_in[10];
    const float* lin2_b = (const float*)d_in[11];
    const float* intw   = (const float*)d_in[12];
    const float* intb   = (const float*)d_in[13];
    const float* poolw  = (const float*)d_in[14];
    const float* poolb  = (const float*)d_in[15];

    float* ws = (float*)d_ws;
    const size_t NHP = (size_t)N_ATOMS * HP;       // 6,080,000
    const size_t TABALL = (size_t)L_LAYERS * M_TAB * HP;   // 3,735,552

    int*   hP    = (int*)ws;                       // NHP
    int*   y1P   = (int*)(ws + NHP);               // NHP; aliases tP, ttabA
    int*   tP    = y1P;
    int*   ttabA = y1P;                            // prep-time alias (3.7M <= NHP)
    int*   aggP  = (int*)(ws + 2 * NHP);           // NHP
    // aggP region aliases — ONLY prep-phase data dead before first gather:
    float4* einfo  = (float4*)aggP;                          // 256,000 f
    int*    deg    = (int*)((float*)aggP + 300000);          // 10,000
    int*    cursor = (int*)((float*)aggP + 310000);          // 10,000
    short*  w1t    = (short*)((float*)aggP + 400000);        // 491,520 shorts
    int*   wtabA = (int*)(ws + 3 * NHP);           // TABALL (persistent)
    int*   rtabP = (int*)(ws + 3 * NHP + TABALL);  // M_TAB*64 = 65,536
    // big weight tiles (4 types x 6 layers x 778,240 shorts)
    short* wtT   = (short*)(ws + 3 * NHP + TABALL + (size_t)M_TAB * 64);
    short* w2t = wtT;
    short* l1t = w2t + (size_t)L_LAYERS * BSTRIDE_BIG;
    short* l2t = l1t + (size_t)L_LAYERS * BSTRIDE_BIG;
    short* itt = l2t + (size_t)L_LAYERS * BSTRIDE_BIG;
    // persistent tail (NOT aliased): esorted, pooled, rowptr, mrow
    float*  tailF   = (float*)(itt + (size_t)L_LAYERS * BSTRIDE_BIG);
    float4* esorted = (float4*)tailF;                        // 256,000 f
    float*  pooled  = tailF + 256000;                        // 76,800 f
    int*    rowptr  = (int*)(tailF + 332800);                // 10,001
    int*    mrow    = rowptr + 10001;                        // 129

    const int* src = eidx;
    const int* dst = eidx + E_EDGES;

    const dim3 blk(256);
    const int QC = HP / 4;
    const dim3 gN   = mfma_grid(N_ATOMS, H_DIM);            // 1600
    const dim3 gTab = mfma_grid(L_LAYERS * M_TAB, H_DIM);   // 960

    // ---- one-time prep (einfo/deg/cursor/w1t alias aggP: dead before gather)
    edge_geom_k<<<(E_EDGES + 255) / 256, blk, 0, stream>>>(pos, src, dst, einfo);
    hipMemsetAsync(deg, 0, 2 * N_ATOMS * sizeof(int), stream);
    hist_k <<<(E_EDGES + 255) / 256, blk, 0, stream>>>(dst, deg);
    scan_k <<<1, 1024, 0, stream>>>(deg, rowptr);
    fill_k <<<(E_EDGES + 255) / 256, blk, 0, stream>>>(dst, einfo, rowptr, cursor, esorted);
    bounds_k <<<1, 256, 0, stream>>>(batch, mrow);
    init_h_k <<<(N_ATOMS * QC + 255) / 256, blk, 0, stream>>>(z, emb, hP);
    rbf_tab_k<<<(M_TAB * 64 + 255) / 256,   blk, 0, stream>>>(rtabP);
    wts_w1_k  <<<dim3(1, 10, 6),   blk, 0, stream>>>(mlp_w1, w1t);
    wts_big_k <<<dim3(10, 10, 24), blk, 0, stream>>>(
        mlp_w2, lin1_w, lin2_w, intw, w2t, l1t, l2t, itt);

    // ---- all 6 layers' filter tables in 2 batched slab GEMMs
    gemm_tab<true, true><<<gTab, blk, 0, stream>>>(
        rtabP, 64, w1t, (size_t)BSTRIDE_W1, mlp_b1,
        ttabA, L_LAYERS * M_TAB, 64, H_DIM);
    gemm_tab<false, false><<<gTab, blk, 0, stream>>>(
        ttabA, HP, w2t, (size_t)BSTRIDE_BIG, mlp_b2,
        wtabA, L_LAYERS * M_TAB, HP, H_DIM);

    for (int k = 0; k < L_LAYERS; ++k) {
        const float* l2b = lin2_b + (size_t)k * H_DIM;
        const float* ib  = intb   + (size_t)k * H_DIM;
        const short* l1 = l1t + (size_t)k * BSTRIDE_BIG;
        const short* l2 = l2t + (size_t)k * BSTRIDE_BIG;
        const short* it = itt + (size_t)k * BSTRIDE_BIG;
        const int*   wtP = wtabA + (size_t)k * M_TAB * HP;

        // y1P = packsplit(h @ lin1)
        gemm_mfma<false, false, false><<<gN, blk, 0, stream>>>(
            hP, HP, l1, nullptr, y1P, N_ATOMS, HP, H_DIM);
        // aggP = packsplit(CSR-gather(y1 * W(d) * C))
        gather_k<<<(N_ATOMS * QC + 255) / 256, blk, 0, stream>>>(
            y1P, wtP, rowptr, esorted, aggP);
        // tP = packsplit(ssp(agg @ lin2 + b))   (aliases y1P)
        gemm_mfma<true, true, false><<<gN, blk, 0, stream>>>(
            aggP, HP, l2, l2b, tP, N_ATOMS, HP, H_DIM);
        // hP = packsplit(unpack(hP) + t @ int_w + ib)
        gemm_mfma<true, false, true><<<gN, blk, 0, stream>>>(
            tP, HP, it, ib, hP, N_ATOMS, HP, H_DIM);
    }

    // segment-mean pool (sorted batch, no atomics), then out = pooled @ pool_w + b
    pool_seg_k<<<B_MOLS, blk, 0, stream>>>(hP, mrow, pooled);
    pool_mm2_k<<<dim3(10, B_MOLS), blk, 0, stream>>>(
        pooled, poolw, poolb, (float*)d_out);
}